// Round 1
// baseline (1598.432 us; speedup 1.0000x reference)
//
#include <hip/hip_runtime.h>
#include <hip/hip_bf16.h>
#include <stdint.h>

#define FEA 60
#define HID 256
#define MACH 22
#define FLAT (MACH * (HID + FEA))   // 6952
#define NEG 0.01f

__device__ __forceinline__ float bf2f(uint16_t u) {
    uint32_t x = ((uint32_t)u) << 16;
    return __uint_as_float(x);
}

// ---------------- dtype detection ----------------
// flags[0] = 1 if float tensors are bf16, 0 if fp32
// flags[1] = 1 if edge_index is int64, 0 if int32
__global__ void k_detect(const uint32_t* ew_w, const uint32_t* ei_w, int* flags) {
    __shared__ int c15, onz;
    if (threadIdx.x == 0) { c15 = 0; onz = 0; }
    __syncthreads();
    int a = 0, b = 0;
    for (int i = threadIdx.x; i < 1024; i += 256) {
        if (ew_w[i] & 0x8000u) a++;          // mantissa bit (fp32) vs sign of even bf16 (=0)
        if (ei_w[2 * i + 1] != 0u) b++;      // odd words zero iff int64
    }
    atomicAdd(&c15, a); atomicAdd(&onz, b);
    __syncthreads();
    if (threadIdx.x == 0) {
        flags[0] = (c15 <= 100) ? 1 : 0;
        flags[1] = (onz < 8) ? 1 : 0;
    }
}

// ---------------- batched input conversion to fp32 ----------------
struct CvtArgs {
    const void* src[14];
    float* dst[14];
    long prefix[15];
    int cnt;
};

__global__ void k_cvt(CvtArgs a, const int* flags) {
    int isbf = flags[0];
    long total = a.prefix[a.cnt];
    for (long i = (long)blockIdx.x * blockDim.x + threadIdx.x; i < total;
         i += (long)gridDim.x * blockDim.x) {
        int t = 0;
        while (i >= a.prefix[t + 1]) t++;
        long j = i - a.prefix[t];
        float v = isbf ? bf2f(((const uint16_t*)a.src[t])[j])
                       : ((const float*)a.src[t])[j];
        a.dst[t][j] = v;
    }
}

__global__ void k_cvt_idx(const void* src, int* dst, long n, const int* flags) {
    int i64 = flags[1];
    for (long i = (long)blockIdx.x * blockDim.x + threadIdx.x; i < n;
         i += (long)gridDim.x * blockDim.x) {
        dst[i] = i64 ? (int)((const long long*)src)[i] : ((const int*)src)[i];
    }
}

// ---------------- degree / norm / CSR ----------------
__global__ void k_init(float* deg, int* count, int* cursor, int n) {
    int i = blockIdx.x * blockDim.x + threadIdx.x;
    if (i < n) { deg[i] = 1.0f; count[i] = 0; cursor[i] = 0; }   // deg starts at self-loop weight 1
}

__global__ void k_deg(const int* ei, const float* ew, float* deg, int* count, int E) {
    int e = blockIdx.x * blockDim.x + threadIdx.x;
    if (e < E) {
        int c = ei[E + e];
        atomicAdd(&deg[c], ew[e]);
        atomicAdd(&count[c], 1);
    }
}

__global__ void k_dinv(float* deg, int n) {
    int i = blockIdx.x * blockDim.x + threadIdx.x;
    if (i < n) {
        double d = (double)deg[i];            // deg >= 1 always (self-loop)
        deg[i] = (float)(1.0 / sqrt(d));
    }
}

__global__ void k_scan(const int* count, int* rowptr, int n) {
    __shared__ int sd[1024];
    __shared__ int carry;
    if (threadIdx.x == 0) carry = 0;
    __syncthreads();
    for (int base = 0; base < n; base += 1024) {
        int i = base + (int)threadIdx.x;
        int v = (i < n) ? count[i] : 0;
        sd[threadIdx.x] = v;
        __syncthreads();
        for (int off = 1; off < 1024; off <<= 1) {
            int t = (threadIdx.x >= (unsigned)off) ? sd[threadIdx.x - off] : 0;
            __syncthreads();
            sd[threadIdx.x] += t;
            __syncthreads();
        }
        if (i < n) rowptr[i] = carry + sd[threadIdx.x] - v;   // exclusive
        __syncthreads();
        if (threadIdx.x == 0) carry += sd[1023];
        __syncthreads();
    }
    if (threadIdx.x == 0) rowptr[n] = carry;
}

__global__ void k_fill(const int* ei, const float* ew, const float* dinv,
                       const int* rowptr, int* cursor, int* adj_src, float* adj_w, int E) {
    int e = blockIdx.x * blockDim.x + threadIdx.x;
    if (e < E) {
        int r = ei[e], c = ei[E + e];
        float w = dinv[r] * ew[e] * dinv[c];
        int pos = rowptr[c] + atomicAdd(&cursor[c], 1);
        adj_src[pos] = r;
        adj_w[pos] = w;
    }
}

// ---------------- generic fp32 tiled GEMM: C[M,N] = A[M,K] @ B[K,N] (+bias, lrelu) ----
// M, N multiples of 64. Grid (N/64, M/64), 256 threads.
__global__ __launch_bounds__(256) void k_gemm(const float* __restrict__ A,
                                              const float* __restrict__ B,
                                              const float* __restrict__ bias,
                                              float* __restrict__ C,
                                              int M, int N, int K, int act) {
    __shared__ float As[16][68];   // [k][m], pad 68: 16B-aligned rows, 2-way banks (free)
    __shared__ float Bs[16][64];   // [k][n]
    int tid = threadIdx.x;
    int row0 = blockIdx.y * 64, col0 = blockIdx.x * 64;
    int tx = tid & 15, ty = tid >> 4;
    float acc[4][4] = {};
    for (int k0 = 0; k0 < K; k0 += 16) {
#pragma unroll
        for (int i = 0; i < 4; i++) {
            int idx = tid + i * 256;
            int r = idx >> 4, c = idx & 15;
            int gk = k0 + c;
            As[c][r] = (gk < K) ? A[(long)(row0 + r) * K + gk] : 0.f;
        }
#pragma unroll
        for (int i = 0; i < 4; i++) {
            int idx = tid + i * 256;
            int r = idx >> 6, c = idx & 63;
            int gk = k0 + r;
            Bs[r][c] = (gk < K) ? B[(long)gk * N + col0 + c] : 0.f;
        }
        __syncthreads();
#pragma unroll
        for (int kk = 0; kk < 16; kk++) {
            float a0[4], b0[4];
#pragma unroll
            for (int i = 0; i < 4; i++) a0[i] = As[kk][ty * 4 + i];
#pragma unroll
            for (int j = 0; j < 4; j++) b0[j] = Bs[kk][tx * 4 + j];
#pragma unroll
            for (int i = 0; i < 4; i++)
#pragma unroll
                for (int j = 0; j < 4; j++) acc[i][j] += a0[i] * b0[j];
        }
        __syncthreads();
    }
#pragma unroll
    for (int i = 0; i < 4; i++)
#pragma unroll
        for (int j = 0; j < 4; j++) {
            int r = row0 + ty * 4 + i, c = col0 + tx * 4 + j;
            float v = acc[i][j];
            if (bias) v += bias[c];
            if (act) v = v > 0.f ? v : NEG * v;
            C[(long)r * N + c] = v;
        }
}

// ---------------- CSR gather-aggregate + bias + lrelu ----------------
// out[i,:] = dinv[i]^2 * hw[i,:] + sum_e w_e * hw[src_e,:] + b ; lrelu
__global__ __launch_bounds__(256) void k_agg(const float* __restrict__ hw,
                                             const float* __restrict__ dinv,
                                             const int* __restrict__ rowptr,
                                             const int* __restrict__ adj_src,
                                             const float* __restrict__ adj_w,
                                             const float* __restrict__ bias,
                                             float* __restrict__ out, int n) {
    int node = blockIdx.x;
    int j = threadIdx.x;
    float di = dinv[node];
    float acc = di * di * hw[(long)node * HID + j];
    int s = rowptr[node], e = rowptr[node + 1];
    __shared__ int ss[64];
    __shared__ float sw[64];
    for (int base = s; base < e; base += 64) {
        int m = e - base; if (m > 64) m = 64;
        if (j < m) { ss[j] = adj_src[base + j]; sw[j] = adj_w[base + j]; }
        __syncthreads();
        for (int t = 0; t < m; t++) acc += sw[t] * hw[(long)ss[t] * HID + j];
        __syncthreads();
    }
    acc += bias[j];
    out[(long)node * HID + j] = acc > 0.f ? acc : NEG * acc;
}

// ---------------- MLP layer 0: z0[B,256] = lrelu(flat[B,6952] @ Wf0 + bf0) --------
// flat is virtual: flat[b][m*316+k] = k<256 ? h2[(b*22+m)][k] : x[(b*22+m)][k-256]
// Block: 16 batch rows x 256 output cols, 256 threads (thread = col j, acc[16]).
__global__ __launch_bounds__(256) void k_mlp0(const float* __restrict__ h2,
                                              const float* __restrict__ xf,
                                              const float* __restrict__ W,
                                              const float* __restrict__ bias,
                                              float* __restrict__ z, int Bn) {
    int b0 = blockIdx.x * 16;
    int j = threadIdx.x;
    __shared__ float sf[32][17];
    float acc[16] = {};
    for (int r0 = 0; r0 < FLAT; r0 += 32) {
#pragma unroll
        for (int t = 0; t < 2; t++) {
            int idx = (int)threadIdx.x + t * 256;
            int rr = idx >> 4, bb = idx & 15;
            int r = r0 + rr;
            float v = 0.f;
            if (r < FLAT) {
                int m = r / (HID + FEA);
                int k = r - m * (HID + FEA);
                int node = (b0 + bb) * MACH + m;
                v = (k < HID) ? h2[(long)node * HID + k] : xf[(long)node * FEA + (k - HID)];
            }
            sf[rr][bb] = v;
        }
        __syncthreads();
        int rmax = FLAT - r0; if (rmax > 32) rmax = 32;
        for (int rr = 0; rr < rmax; rr++) {
            float w = W[(long)(r0 + rr) * HID + j];
#pragma unroll
            for (int bb = 0; bb < 16; bb++) acc[bb] += sf[rr][bb] * w;
        }
        __syncthreads();
    }
    float bj = bias[j];
#pragma unroll
    for (int bb = 0; bb < 16; bb++) {
        float v = acc[bb] + bj;
        v = v > 0.f ? v : NEG * v;
        z[(long)(b0 + bb) * HID + j] = v;
    }
}

// ---------------- output layer: out[B,4] = z2 @ Wo + bo (dtype per flag) ---------
__global__ void k_out(const float* __restrict__ z2, const float* __restrict__ Wo,
                      const float* __restrict__ bo, void* out, const int* flags, int Bn) {
    int idx = blockIdx.x * blockDim.x + threadIdx.x;
    if (idx >= Bn * 4) return;
    int b = idx >> 2, o = idx & 3;
    float acc = bo[o];
    const float* zr = z2 + (long)b * HID;
    for (int k = 0; k < HID; k++) acc += zr[k] * Wo[k * 4 + o];
    if (flags[0]) ((__hip_bfloat16*)out)[idx] = __float2bfloat16(acc);
    else          ((float*)out)[idx] = acc;
}

// ---------------- host ----------------
extern "C" void kernel_launch(void* const* d_in, const int* in_sizes, int n_in,
                              void* d_out, int out_size, void* d_ws, size_t ws_size,
                              hipStream_t stream) {
    const int N  = in_sizes[0] / FEA;   // 45056
    const int E  = in_sizes[2];         // 720896
    const int Bn = N / MACH;            // 2048

    char* ws = (char*)d_ws;
    size_t off = 0;
    auto alloc = [&](size_t bytes) -> char* {
        char* p = ws + off;
        off = (off + bytes + 255) & ~(size_t)255;
        return p;
    };

    int*   flags   = (int*)  alloc(64);
    float* xf      = (float*)alloc((size_t)N * FEA * 4);
    float* ew      = (float*)alloc((size_t)E * 4);
    float* W1      = (float*)alloc((size_t)FEA * HID * 4);
    float* b1      = (float*)alloc(HID * 4);
    float* W2      = (float*)alloc((size_t)HID * HID * 4);
    float* b2      = (float*)alloc(HID * 4);
    float* Wf0     = (float*)alloc((size_t)FLAT * HID * 4);
    float* bf0     = (float*)alloc(HID * 4);
    float* Wf1     = (float*)alloc((size_t)HID * HID * 4);
    float* bf1     = (float*)alloc(HID * 4);
    float* Wf2     = (float*)alloc((size_t)HID * HID * 4);
    float* bf2     = (float*)alloc(HID * 4);
    float* Wo      = (float*)alloc((size_t)HID * 4 * 4);
    float* bo      = (float*)alloc(4 * 4);
    int*   ei      = (int*)  alloc((size_t)2 * E * 4);
    float* dinv    = (float*)alloc((size_t)N * 4);
    int*   count   = (int*)  alloc((size_t)N * 4);
    int*   cursor  = (int*)  alloc((size_t)N * 4);
    int*   rowptr  = (int*)  alloc((size_t)(N + 1) * 4);
    int*   adj_src = (int*)  alloc((size_t)E * 4);
    float* adj_w   = (float*)alloc((size_t)E * 4);
    float* P       = (float*)alloc((size_t)N * HID * 4);   // hw buffer
    float* Q       = (float*)alloc((size_t)N * HID * 4);   // h1 / h2 buffer
    float* z0      = (float*)alloc((size_t)Bn * HID * 4);
    float* z1      = (float*)alloc((size_t)Bn * HID * 4);
    (void)ws_size; (void)n_in; (void)out_size;

    // 1. dtype detection
    k_detect<<<1, 256, 0, stream>>>((const uint32_t*)d_in[2], (const uint32_t*)d_in[1], flags);

    // 2. convert all float tensors to fp32
    CvtArgs ca{};
    const void* srcs[14] = { d_in[0], d_in[2], d_in[3], d_in[4], d_in[5], d_in[6],
                             d_in[7], d_in[8], d_in[9], d_in[10], d_in[11], d_in[12],
                             d_in[13], d_in[14] };
    float* dsts[14] = { xf, ew, W1, b1, W2, b2, Wf0, bf0, Wf1, bf1, Wf2, bf2, Wo, bo };
    long ns[14] = { (long)N * FEA, E, (long)FEA * HID, HID, (long)HID * HID, HID,
                    (long)FLAT * HID, HID, (long)HID * HID, HID, (long)HID * HID, HID,
                    (long)HID * 4, 4 };
    ca.cnt = 14;
    ca.prefix[0] = 0;
    for (int t = 0; t < 14; t++) {
        ca.src[t] = srcs[t];
        ca.dst[t] = dsts[t];
        ca.prefix[t + 1] = ca.prefix[t] + ns[t];
    }
    k_cvt<<<4096, 256, 0, stream>>>(ca, flags);
    k_cvt_idx<<<4096, 256, 0, stream>>>(d_in[1], ei, (long)2 * E, flags);

    // 3. degree + norm + CSR
    k_init<<<(N + 255) / 256, 256, 0, stream>>>(dinv, count, cursor, N);   // dinv buf holds deg first
    k_deg<<<(E + 255) / 256, 256, 0, stream>>>(ei, ew, dinv, count, E);
    k_dinv<<<(N + 255) / 256, 256, 0, stream>>>(dinv, N);
    k_scan<<<1, 1024, 0, stream>>>(count, rowptr, N);
    k_fill<<<(E + 255) / 256, 256, 0, stream>>>(ei, ew, dinv, rowptr, cursor, adj_src, adj_w, E);

    // 4. GCN layer 1
    dim3 g1(HID / 64, N / 64);
    k_gemm<<<g1, 256, 0, stream>>>(xf, W1, nullptr, P, N, HID, FEA, 0);
    k_agg<<<N, 256, 0, stream>>>(P, dinv, rowptr, adj_src, adj_w, b1, Q, N);

    // 5. GCN layer 2
    k_gemm<<<g1, 256, 0, stream>>>(Q, W2, nullptr, P, N, HID, HID, 0);
    k_agg<<<N, 256, 0, stream>>>(P, dinv, rowptr, adj_src, adj_w, b2, Q, N);   // h2 -> Q

    // 6. MLP head
    k_mlp0<<<Bn / 16, 256, 0, stream>>>(Q, xf, Wf0, bf0, z0, Bn);
    dim3 g2(HID / 64, Bn / 64);
    k_gemm<<<g2, 256, 0, stream>>>(z0, Wf1, bf1, z1, Bn, HID, HID, 1);
    k_gemm<<<g2, 256, 0, stream>>>(z1, Wf2, bf2, z0, Bn, HID, HID, 1);
    k_out<<<(Bn * 4 + 255) / 256, 256, 0, stream>>>(z0, Wo, bo, d_out, flags, Bn);
}

// Round 2
// 896.372 us; speedup vs baseline: 1.7832x; 1.7832x over previous
//
#include <hip/hip_runtime.h>
#include <hip/hip_bf16.h>
#include <stdint.h>

#define FEA 60
#define HID 256
#define MACH 22
#define PERM (HID + FEA)            // 316
#define FLAT (MACH * PERM)          // 6952
#define NEG 0.01f

__device__ __forceinline__ float bf2f(uint16_t u) {
    uint32_t x = ((uint32_t)u) << 16;
    return __uint_as_float(x);
}

// ---------------- dtype detection ----------------
__global__ void k_detect(const uint32_t* ew_w, const uint32_t* ei_w, int* flags) {
    __shared__ int c15, onz;
    if (threadIdx.x == 0) { c15 = 0; onz = 0; }
    __syncthreads();
    int a = 0, b = 0;
    for (int i = threadIdx.x; i < 1024; i += 256) {
        if (ew_w[i] & 0x8000u) a++;
        if (ei_w[2 * i + 1] != 0u) b++;
    }
    atomicAdd(&c15, a); atomicAdd(&onz, b);
    __syncthreads();
    if (threadIdx.x == 0) {
        flags[0] = (c15 <= 100) ? 1 : 0;
        flags[1] = (onz < 8) ? 1 : 0;
    }
}

// ---------------- batched input conversion to fp32 ----------------
struct CvtArgs {
    const void* src[14];
    float* dst[14];
    long prefix[15];
    int cnt;
};

__global__ void k_cvt(CvtArgs a, const int* flags) {
    int isbf = flags[0];
    long total = a.prefix[a.cnt];
    for (long i = (long)blockIdx.x * blockDim.x + threadIdx.x; i < total;
         i += (long)gridDim.x * blockDim.x) {
        int t = 0;
        while (i >= a.prefix[t + 1]) t++;
        long j = i - a.prefix[t];
        float v = isbf ? bf2f(((const uint16_t*)a.src[t])[j])
                       : ((const float*)a.src[t])[j];
        a.dst[t][j] = v;
    }
}

__global__ void k_cvt_idx(const void* src, int* dst, long n, const int* flags) {
    int i64 = flags[1];
    for (long i = (long)blockIdx.x * blockDim.x + threadIdx.x; i < n;
         i += (long)gridDim.x * blockDim.x) {
        dst[i] = i64 ? (int)((const long long*)src)[i] : ((const int*)src)[i];
    }
}

// ---------------- degree / norm / CSR ----------------
__global__ void k_init(float* deg, int* count, int* cursor, int n) {
    int i = blockIdx.x * blockDim.x + threadIdx.x;
    if (i < n) { deg[i] = 1.0f; count[i] = 0; cursor[i] = 0; }
}

__global__ void k_deg(const int* ei, const float* ew, float* deg, int* count, int E) {
    int e = blockIdx.x * blockDim.x + threadIdx.x;
    if (e < E) {
        int c = ei[E + e];
        atomicAdd(&deg[c], ew[e]);
        atomicAdd(&count[c], 1);
    }
}

__global__ void k_dinv(float* deg, int n) {
    int i = blockIdx.x * blockDim.x + threadIdx.x;
    if (i < n) {
        double d = (double)deg[i];
        deg[i] = (float)(1.0 / sqrt(d));
    }
}

__global__ void k_scan(const int* count, int* rowptr, int n) {
    __shared__ int sd[1024];
    __shared__ int carry;
    if (threadIdx.x == 0) carry = 0;
    __syncthreads();
    for (int base = 0; base < n; base += 1024) {
        int i = base + (int)threadIdx.x;
        int v = (i < n) ? count[i] : 0;
        sd[threadIdx.x] = v;
        __syncthreads();
        for (int off = 1; off < 1024; off <<= 1) {
            int t = (threadIdx.x >= (unsigned)off) ? sd[threadIdx.x - off] : 0;
            __syncthreads();
            sd[threadIdx.x] += t;
            __syncthreads();
        }
        if (i < n) rowptr[i] = carry + sd[threadIdx.x] - v;
        __syncthreads();
        if (threadIdx.x == 0) carry += sd[1023];
        __syncthreads();
    }
    if (threadIdx.x == 0) rowptr[n] = carry;
}

__global__ void k_fill(const int* ei, const float* ew, const float* dinv,
                       const int* rowptr, int* cursor, int* adj_src, float* adj_w, int E) {
    int e = blockIdx.x * blockDim.x + threadIdx.x;
    if (e < E) {
        int r = ei[e], c = ei[E + e];
        float w = dinv[r] * ew[e] * dinv[c];
        int pos = rowptr[c] + atomicAdd(&cursor[c], 1);
        adj_src[pos] = r;
        adj_w[pos] = w;
    }
}

// ---------------- generic fp32 tiled GEMM (no split) ----------------
__global__ __launch_bounds__(256) void k_gemm(const float* __restrict__ A,
                                              const float* __restrict__ B,
                                              const float* __restrict__ bias,
                                              float* __restrict__ C,
                                              int M, int N, int K, int act) {
    __shared__ float As[16][68];
    __shared__ float Bs[16][64];
    int tid = threadIdx.x;
    int row0 = blockIdx.y * 64, col0 = blockIdx.x * 64;
    int tx = tid & 15, ty = tid >> 4;
    float acc[4][4] = {};
    for (int k0 = 0; k0 < K; k0 += 16) {
#pragma unroll
        for (int i = 0; i < 4; i++) {
            int idx = tid + i * 256;
            int r = idx >> 4, c = idx & 15;
            int gk = k0 + c;
            As[c][r] = (gk < K) ? A[(long)(row0 + r) * K + gk] : 0.f;
        }
#pragma unroll
        for (int i = 0; i < 4; i++) {
            int idx = tid + i * 256;
            int r = idx >> 6, c = idx & 63;
            int gk = k0 + r;
            Bs[r][c] = (gk < K) ? B[(long)gk * N + col0 + c] : 0.f;
        }
        __syncthreads();
#pragma unroll
        for (int kk = 0; kk < 16; kk++) {
            float a0[4], b0[4];
#pragma unroll
            for (int i = 0; i < 4; i++) a0[i] = As[kk][ty * 4 + i];
#pragma unroll
            for (int j = 0; j < 4; j++) b0[j] = Bs[kk][tx * 4 + j];
#pragma unroll
            for (int i = 0; i < 4; i++)
#pragma unroll
                for (int j = 0; j < 4; j++) acc[i][j] += a0[i] * b0[j];
        }
        __syncthreads();
    }
#pragma unroll
    for (int i = 0; i < 4; i++)
#pragma unroll
        for (int j = 0; j < 4; j++) {
            int r = row0 + ty * 4 + i, c = col0 + tx * 4 + j;
            float v = acc[i][j];
            if (bias) v += bias[c];
            if (act) v = v > 0.f ? v : NEG * v;
            C[(long)r * N + c] = v;
        }
}

// ---------------- split-K fp32 GEMM: partials, plain A ----------------
// grid (N/64, M/64, S); each z-slice covers K range [z*Kc, min(K,(z+1)*Kc))
__global__ __launch_bounds__(256) void k_gemm_sk(const float* __restrict__ A,
                                                 const float* __restrict__ B,
                                                 float* __restrict__ part,
                                                 int M, int N, int K, int Kc) {
    __shared__ float As[16][68];
    __shared__ float Bs[16][64];
    int tid = threadIdx.x;
    int row0 = blockIdx.y * 64, col0 = blockIdx.x * 64;
    int kbeg = blockIdx.z * Kc;
    int kend = kbeg + Kc; if (kend > K) kend = K;
    int tx = tid & 15, ty = tid >> 4;
    float acc[4][4] = {};
    for (int k0 = kbeg; k0 < kend; k0 += 16) {
#pragma unroll
        for (int i = 0; i < 4; i++) {
            int idx = tid + i * 256;
            int r = idx >> 4, c = idx & 15;
            int gk = k0 + c;
            As[c][r] = (gk < kend) ? A[(long)(row0 + r) * K + gk] : 0.f;
        }
#pragma unroll
        for (int i = 0; i < 4; i++) {
            int idx = tid + i * 256;
            int r = idx >> 6, c = idx & 63;
            int gk = k0 + r;
            Bs[r][c] = (gk < kend) ? B[(long)gk * N + col0 + c] : 0.f;
        }
        __syncthreads();
#pragma unroll
        for (int kk = 0; kk < 16; kk++) {
            float a0[4], b0[4];
#pragma unroll
            for (int i = 0; i < 4; i++) a0[i] = As[kk][ty * 4 + i];
#pragma unroll
            for (int j = 0; j < 4; j++) b0[j] = Bs[kk][tx * 4 + j];
#pragma unroll
            for (int i = 0; i < 4; i++)
#pragma unroll
                for (int j = 0; j < 4; j++) acc[i][j] += a0[i] * b0[j];
        }
        __syncthreads();
    }
    float* out = part + (long)blockIdx.z * M * N;
#pragma unroll
    for (int i = 0; i < 4; i++)
#pragma unroll
        for (int j = 0; j < 4; j++)
            out[(long)(row0 + ty * 4 + i) * N + col0 + tx * 4 + j] = acc[i][j];
}

// ---------------- split-K fp32 GEMM with VIRTUAL flat A (mlp0) ----------------
// A[b][gk] = (k2<HID) ? h2[(b*22+m)][k2] : x[(b*22+m)][k2-HID], m=gk/316, k2=gk%316
__global__ __launch_bounds__(256) void k_gemm_sk_flat(const float* __restrict__ h2,
                                                      const float* __restrict__ xf,
                                                      const float* __restrict__ B,
                                                      float* __restrict__ part,
                                                      int M, int N, int K, int Kc) {
    __shared__ float As[16][68];
    __shared__ float Bs[16][64];
    int tid = threadIdx.x;
    int row0 = blockIdx.y * 64, col0 = blockIdx.x * 64;
    int kbeg = blockIdx.z * Kc;
    int kend = kbeg + Kc; if (kend > K) kend = K;
    int tx = tid & 15, ty = tid >> 4;
    float acc[4][4] = {};
    for (int k0 = kbeg; k0 < kend; k0 += 16) {
#pragma unroll
        for (int i = 0; i < 4; i++) {
            int idx = tid + i * 256;
            int r = idx >> 4, c = idx & 15;
            int gk = k0 + c;
            float v = 0.f;
            if (gk < kend) {
                int m = gk / PERM;
                int k2 = gk - m * PERM;
                long node = (long)(row0 + r) * MACH + m;
                v = (k2 < HID) ? h2[node * HID + k2] : xf[node * FEA + (k2 - HID)];
            }
            As[c][r] = v;
        }
#pragma unroll
        for (int i = 0; i < 4; i++) {
            int idx = tid + i * 256;
            int r = idx >> 6, c = idx & 63;
            int gk = k0 + r;
            Bs[r][c] = (gk < kend) ? B[(long)gk * N + col0 + c] : 0.f;
        }
        __syncthreads();
#pragma unroll
        for (int kk = 0; kk < 16; kk++) {
            float a0[4], b0[4];
#pragma unroll
            for (int i = 0; i < 4; i++) a0[i] = As[kk][ty * 4 + i];
#pragma unroll
            for (int j = 0; j < 4; j++) b0[j] = Bs[kk][tx * 4 + j];
#pragma unroll
            for (int i = 0; i < 4; i++)
#pragma unroll
                for (int j = 0; j < 4; j++) acc[i][j] += a0[i] * b0[j];
        }
        __syncthreads();
    }
    float* out = part + (long)blockIdx.z * M * N;
#pragma unroll
    for (int i = 0; i < 4; i++)
#pragma unroll
        for (int j = 0; j < 4; j++)
            out[(long)(row0 + ty * 4 + i) * N + col0 + tx * 4 + j] = acc[i][j];
}

// ---------------- reduce partials + bias + leaky relu ----------------
__global__ void k_reduce(const float* __restrict__ part, const float* __restrict__ bias,
                         float* __restrict__ out, int MN, int S) {
    int i = blockIdx.x * blockDim.x + threadIdx.x;
    if (i >= MN) return;
    float v = 0.f;
    for (int s = 0; s < S; s++) v += part[(long)s * MN + i];
    v += bias[i & (HID - 1)];
    out[i] = v > 0.f ? v : NEG * v;
}

// ---------------- CSR gather-aggregate, float4, one wave per node ----------------
__global__ __launch_bounds__(256) void k_agg4(const float* __restrict__ hw,
                                              const float* __restrict__ dinv,
                                              const int* __restrict__ rowptr,
                                              const int* __restrict__ adj_src,
                                              const float* __restrict__ adj_w,
                                              const float* __restrict__ bias,
                                              float* __restrict__ out, int n) {
    __shared__ int ssrc[4][64];
    __shared__ float swt[4][64];
    int wv = threadIdx.x >> 6;
    int lane = threadIdx.x & 63;
    int node = blockIdx.x * 4 + wv;
    if (node >= n) return;
    const float4* hw4 = (const float4*)hw;
    float di = dinv[node];
    float c2 = di * di;
    float4 h = hw4[(long)node * 64 + lane];
    float4 acc = make_float4(c2 * h.x, c2 * h.y, c2 * h.z, c2 * h.w);
    int s = rowptr[node], e = rowptr[node + 1];
    for (int base = s; base < e; base += 64) {
        int m = e - base; if (m > 64) m = 64;
        if (lane < m) { ssrc[wv][lane] = adj_src[base + lane]; swt[wv][lane] = adj_w[base + lane]; }
        // wave-private LDS region: no __syncthreads needed (single-wave ordering via lgkmcnt)
        for (int t = 0; t < m; t++) {
            int src = ssrc[wv][t];
            float w = swt[wv][t];
            float4 v = hw4[(long)src * 64 + lane];
            acc.x += w * v.x; acc.y += w * v.y; acc.z += w * v.z; acc.w += w * v.w;
        }
    }
    float4 b4 = ((const float4*)bias)[lane];
    acc.x += b4.x; acc.y += b4.y; acc.z += b4.z; acc.w += b4.w;
    acc.x = acc.x > 0.f ? acc.x : NEG * acc.x;
    acc.y = acc.y > 0.f ? acc.y : NEG * acc.y;
    acc.z = acc.z > 0.f ? acc.z : NEG * acc.z;
    acc.w = acc.w > 0.f ? acc.w : NEG * acc.w;
    ((float4*)out)[(long)node * 64 + lane] = acc;
}

// ---------------- output layer ----------------
__global__ void k_out(const float* __restrict__ z2, const float* __restrict__ Wo,
                      const float* __restrict__ bo, void* out, const int* flags, int Bn) {
    int idx = blockIdx.x * blockDim.x + threadIdx.x;
    if (idx >= Bn * 4) return;
    int b = idx >> 2, o = idx & 3;
    float acc = bo[o];
    const float* zr = z2 + (long)b * HID;
    for (int k = 0; k < HID; k++) acc += zr[k] * Wo[k * 4 + o];
    if (flags[0]) ((__hip_bfloat16*)out)[idx] = __float2bfloat16(acc);
    else          ((float*)out)[idx] = acc;
}

// ---------------- host ----------------
extern "C" void kernel_launch(void* const* d_in, const int* in_sizes, int n_in,
                              void* d_out, int out_size, void* d_ws, size_t ws_size,
                              hipStream_t stream) {
    const int N  = in_sizes[0] / FEA;   // 45056
    const int E  = in_sizes[2];         // 720896
    const int Bn = N / MACH;            // 2048

    char* ws = (char*)d_ws;
    size_t off = 0;
    auto alloc = [&](size_t bytes) -> char* {
        char* p = ws + off;
        off = (off + bytes + 255) & ~(size_t)255;
        return p;
    };

    int*   flags   = (int*)  alloc(64);
    float* xf      = (float*)alloc((size_t)N * FEA * 4);
    float* ew      = (float*)alloc((size_t)E * 4);
    float* W1      = (float*)alloc((size_t)FEA * HID * 4);
    float* b1      = (float*)alloc(HID * 4);
    float* W2      = (float*)alloc((size_t)HID * HID * 4);
    float* b2      = (float*)alloc(HID * 4);
    float* Wf0     = (float*)alloc((size_t)FLAT * HID * 4);
    float* bf0     = (float*)alloc(HID * 4);
    float* Wf1     = (float*)alloc((size_t)HID * HID * 4);
    float* bf1     = (float*)alloc(HID * 4);
    float* Wf2     = (float*)alloc((size_t)HID * HID * 4);
    float* bf2     = (float*)alloc(HID * 4);
    float* Wo      = (float*)alloc((size_t)HID * 4 * 4);
    float* bo      = (float*)alloc(4 * 4);
    int*   ei      = (int*)  alloc((size_t)2 * E * 4);
    float* dinv    = (float*)alloc((size_t)N * 4);
    int*   count   = (int*)  alloc((size_t)N * 4);
    int*   cursor  = (int*)  alloc((size_t)N * 4);
    int*   rowptr  = (int*)  alloc((size_t)(N + 1) * 4);
    int*   adj_src = (int*)  alloc((size_t)E * 4);
    float* adj_w   = (float*)alloc((size_t)E * 4);
    float* P       = (float*)alloc((size_t)N * HID * 4);   // hw buffer
    float* Q       = (float*)alloc((size_t)N * HID * 4);   // h1 / h2 buffer
    float* z0      = (float*)alloc((size_t)Bn * HID * 4);
    float* z1      = (float*)alloc((size_t)Bn * HID * 4);
    float* part    = (float*)alloc((size_t)8 * Bn * HID * 4);  // split-K partials (16.8 MB)
    (void)ws_size; (void)n_in; (void)out_size;

    // 1. dtype detection
    k_detect<<<1, 256, 0, stream>>>((const uint32_t*)d_in[2], (const uint32_t*)d_in[1], flags);

    // 2. convert all float tensors to fp32
    CvtArgs ca{};
    const void* srcs[14] = { d_in[0], d_in[2], d_in[3], d_in[4], d_in[5], d_in[6],
                             d_in[7], d_in[8], d_in[9], d_in[10], d_in[11], d_in[12],
                             d_in[13], d_in[14] };
    float* dsts[14] = { xf, ew, W1, b1, W2, b2, Wf0, bf0, Wf1, bf1, Wf2, bf2, Wo, bo };
    long ns[14] = { (long)N * FEA, E, (long)FEA * HID, HID, (long)HID * HID, HID,
                    (long)FLAT * HID, HID, (long)HID * HID, HID, (long)HID * HID, HID,
                    (long)HID * 4, 4 };
    ca.cnt = 14;
    ca.prefix[0] = 0;
    for (int t = 0; t < 14; t++) {
        ca.src[t] = srcs[t];
        ca.dst[t] = dsts[t];
        ca.prefix[t + 1] = ca.prefix[t] + ns[t];
    }
    k_cvt<<<4096, 256, 0, stream>>>(ca, flags);
    k_cvt_idx<<<4096, 256, 0, stream>>>(d_in[1], ei, (long)2 * E, flags);

    // 3. degree + norm + CSR
    k_init<<<(N + 255) / 256, 256, 0, stream>>>(dinv, count, cursor, N);
    k_deg<<<(E + 255) / 256, 256, 0, stream>>>(ei, ew, dinv, count, E);
    k_dinv<<<(N + 255) / 256, 256, 0, stream>>>(dinv, N);
    k_scan<<<1, 1024, 0, stream>>>(count, rowptr, N);
    k_fill<<<(E + 255) / 256, 256, 0, stream>>>(ei, ew, dinv, rowptr, cursor, adj_src, adj_w, E);

    // 4. GCN layer 1
    dim3 g1(HID / 64, N / 64);
    k_gemm<<<g1, 256, 0, stream>>>(xf, W1, nullptr, P, N, HID, FEA, 0);
    k_agg4<<<(N + 3) / 4, 256, 0, stream>>>(P, dinv, rowptr, adj_src, adj_w, b1, Q, N);

    // 5. GCN layer 2
    k_gemm<<<g1, 256, 0, stream>>>(Q, W2, nullptr, P, N, HID, HID, 0);
    k_agg4<<<(N + 3) / 4, 256, 0, stream>>>(P, dinv, rowptr, adj_src, adj_w, b2, Q, N);

    // 6. MLP head — split-K GEMMs
    // mlp0: M=2048, N=256, K=6952, S=8, Kc=880 (multiple of 16)
    {
        int S = 8, Kc = 880;
        dim3 g(HID / 64, Bn / 64, S);
        k_gemm_sk_flat<<<g, 256, 0, stream>>>(Q, xf, Wf0, part, Bn, HID, FLAT, Kc);
        k_reduce<<<(Bn * HID + 255) / 256, 256, 0, stream>>>(part, bf0, z0, Bn * HID, S);
    }
    // mlp1: K=256, S=4, Kc=64
    {
        int S = 4, Kc = 64;
        dim3 g(HID / 64, Bn / 64, S);
        k_gemm_sk<<<g, 256, 0, stream>>>(z0, Wf1, part, Bn, HID, HID, Kc);
        k_reduce<<<(Bn * HID + 255) / 256, 256, 0, stream>>>(part, bf1, z1, Bn * HID, S);
    }
    // mlp2: K=256, S=4, Kc=64
    {
        int S = 4, Kc = 64;
        dim3 g(HID / 64, Bn / 64, S);
        k_gemm_sk<<<g, 256, 0, stream>>>(z1, Wf2, part, Bn, HID, HID, Kc);
        k_reduce<<<(Bn * HID + 255) / 256, 256, 0, stream>>>(part, bf2, z0, Bn * HID, S);
    }
    k_out<<<(Bn * 4 + 255) / 256, 256, 0, stream>>>(z0, Wo, bo, d_out, flags, Bn);
}

// Round 3
// 484.577 us; speedup vs baseline: 3.2986x; 1.8498x over previous
//
#include <hip/hip_runtime.h>
#include <stdint.h>

#define FEA 60
#define HID 256
#define MACH 22
#define PERM 316            // HID + FEA
#define FLATK 6952          // MACH * PERM
#define FLATP 6976          // padded to multiple of 64
#define NEG 0.01f

typedef __bf16 bf16x8 __attribute__((ext_vector_type(8)));
typedef float f32x4 __attribute__((ext_vector_type(4)));

__device__ __forceinline__ float bf2f(uint16_t u) {
    return __uint_as_float(((uint32_t)u) << 16);
}
__device__ __forceinline__ uint16_t f2bf(float f) {   // RNE
    uint32_t x = __float_as_uint(f);
    return (uint16_t)((x + 0x7fffu + ((x >> 16) & 1u)) >> 16);
}

// ---------------- dtype detection ----------------
// flags[0]=1 if float tensors are bf16 ; flags[1]=1 if edge_index is int64
__global__ void k_detect(const uint32_t* ew_w, const uint32_t* ei_w, int* flags) {
    __shared__ int c15, onz;
    if (threadIdx.x == 0) { c15 = 0; onz = 0; }
    __syncthreads();
    int a = 0, b = 0;
    for (int i = threadIdx.x; i < 1024; i += 256) {
        if (ew_w[i] & 0x8000u) a++;
        if (ei_w[2 * i + 1] != 0u) b++;
    }
    atomicAdd(&c15, a); atomicAdd(&onz, b);
    __syncthreads();
    if (threadIdx.x == 0) {
        flags[0] = (c15 <= 100) ? 1 : 0;
        flags[1] = (onz < 8) ? 1 : 0;
    }
}

// ---------------- fp32 conversions (small tensors + edge_weight) ----------------
struct Cvt8 {
    const void* src[8];
    float* dst[8];
    long prefix[9];
};

__global__ void k_cvt_f32(Cvt8 a, const int* flags) {
    int isbf = flags[0];
    long total = a.prefix[8];
    for (long i = (long)blockIdx.x * blockDim.x + threadIdx.x; i < total;
         i += (long)gridDim.x * blockDim.x) {
        int t = 0;
        while (i >= a.prefix[t + 1]) t++;
        long j = i - a.prefix[t];
        a.dst[t][j] = isbf ? bf2f(((const uint16_t*)a.src[t])[j])
                           : ((const float*)a.src[t])[j];
    }
}

__global__ void k_cvt_idx(const void* src, int* dst, long n, const int* flags) {
    int i64 = flags[1];
    for (long i = (long)blockIdx.x * blockDim.x + threadIdx.x; i < n;
         i += (long)gridDim.x * blockDim.x) {
        dst[i] = i64 ? (int)((const long long*)src)[i] : ((const int*)src)[i];
    }
}

// x [N][60] (bf16 or f32) -> x64 bf16 [N][64], cols 60..63 = 0
__global__ void k_cvt_x(const void* src, uint16_t* dst, int n, const int* flags) {
    int isbf = flags[0];
    long total = (long)n * 64;
    for (long i = (long)blockIdx.x * blockDim.x + threadIdx.x; i < total;
         i += (long)gridDim.x * blockDim.x) {
        int col = (int)(i & 63);
        long row = i >> 6;
        uint16_t v = 0;
        if (col < FEA) {
            long s = row * FEA + col;
            v = isbf ? ((const uint16_t*)src)[s] : f2bf(((const float*)src)[s]);
        }
        dst[i] = v;
    }
}

// W [K][256] -> Wt bf16 [256][Kpad], zero-fill k>=K. Grid (Kpad/64, 4), 256 thr.
__global__ void k_transp(const void* W, uint16_t* Wt, int K, int Kpad, const int* flags) {
    __shared__ uint16_t s[64][65];
    int isbf = flags[0];
    int k0 = blockIdx.x * 64, n0 = blockIdx.y * 64;
    int t = threadIdx.x;
#pragma unroll
    for (int i = 0; i < 16; i++) {
        int idx = t + i * 256;
        int kk = idx >> 6, nn = idx & 63;
        int k = k0 + kk;
        uint16_t v = 0;
        if (k < K) {
            long off = (long)k * HID + n0 + nn;
            v = isbf ? ((const uint16_t*)W)[off] : f2bf(((const float*)W)[off]);
        }
        s[kk][nn] = v;
    }
    __syncthreads();
#pragma unroll
    for (int i = 0; i < 16; i++) {
        int idx = t + i * 256;
        int nn = idx >> 6, kk = idx & 63;
        Wt[(long)(n0 + nn) * Kpad + k0 + kk] = s[kk][nn];
    }
}

// ---------------- degree / norm / CSR ----------------
__global__ void k_init(float* deg, int* count, int* cursor, int n) {
    int i = blockIdx.x * blockDim.x + threadIdx.x;
    if (i < n) { deg[i] = 1.0f; count[i] = 0; cursor[i] = 0; }
}

__global__ void k_deg(const int* ei, const float* ew, float* deg, int* count, int E) {
    int e = blockIdx.x * blockDim.x + threadIdx.x;
    if (e < E) {
        int c = ei[E + e];
        atomicAdd(&deg[c], ew[e]);
        atomicAdd(&count[c], 1);
    }
}

__global__ void k_dinv(float* deg, int n) {
    int i = blockIdx.x * blockDim.x + threadIdx.x;
    if (i < n) {
        double d = (double)deg[i];
        deg[i] = (float)(1.0 / sqrt(d));
    }
}

// hierarchical exclusive scan of count[45056] -> rowptr ; 44 blocks x 1024
__global__ void k_scan1(const int* count, int* rowptr, int* bsum, int n) {
    __shared__ int sd[1024];
    int i = blockIdx.x * 1024 + threadIdx.x;
    int v = (i < n) ? count[i] : 0;
    sd[threadIdx.x] = v;
    __syncthreads();
    for (int off = 1; off < 1024; off <<= 1) {
        int t = (threadIdx.x >= (unsigned)off) ? sd[threadIdx.x - off] : 0;
        __syncthreads();
        sd[threadIdx.x] += t;
        __syncthreads();
    }
    if (i < n) rowptr[i] = sd[threadIdx.x] - v;
    if (threadIdx.x == 1023) bsum[blockIdx.x] = sd[1023];
}

__global__ void k_scan2(int* bsum, int* boffs, int* rowptr, int nb, int n) {
    int acc = 0;
    for (int i = 0; i < nb; i++) { boffs[i] = acc; acc += bsum[i]; }
    rowptr[n] = acc;
}

__global__ void k_scan3(int* rowptr, const int* boffs, int n) {
    int i = blockIdx.x * 1024 + threadIdx.x;
    if (i < n) rowptr[i] += boffs[blockIdx.x];
}

__global__ void k_fill(const int* ei, const float* ew, const float* dinv,
                       const int* rowptr, int* cursor, int* adj_src, float* adj_w, int E) {
    int e = blockIdx.x * blockDim.x + threadIdx.x;
    if (e < E) {
        int r = ei[e], c = ei[E + e];
        float w = dinv[r] * ew[e] * dinv[c];
        int pos = rowptr[c] + atomicAdd(&cursor[c], 1);
        adj_src[pos] = r;
        adj_w[pos] = w;
    }
}

// ---------------- bf16 MFMA GEMM ----------------
// C[M,256] = A(bf16 [M][K]) @ Bt(bf16 [256][K])^T over K-slice blockIdx.z.
// Tile 128x128, 4 waves, each wave 64x64 (4x4 tiles of 16x16x32 MFMA).
// part != 0 : write fp32 partials part[z][M][256] ; else write bf16 to outb.
__global__ __launch_bounds__(256) void k_mgemm(const uint16_t* __restrict__ A,
                                               const uint16_t* __restrict__ Bt,
                                               float* __restrict__ part,
                                               uint16_t* __restrict__ outb,
                                               int M, int K, int Kc) {
    __shared__ uint16_t As[128 * 40];   // row-major [128][40], 8 k-chunk pad->40
    __shared__ uint16_t Bs[128 * 40];
    int tid = threadIdx.x;
    int lane = tid & 63, wv = tid >> 6;
    int quad = lane >> 4, l15 = lane & 15;
    int row0 = blockIdx.y * 128, col0 = blockIdx.x * 128;
    int kbeg = blockIdx.z * Kc;
    int kend = kbeg + Kc; if (kend > K) kend = K;
    int arow = (wv >> 1) * 64;
    int bcol = (wv & 1) * 64;

    f32x4 acc[4][4];
#pragma unroll
    for (int i = 0; i < 4; i++)
#pragma unroll
        for (int j = 0; j < 4; j++) acc[i][j] = (f32x4){0.f, 0.f, 0.f, 0.f};

    for (int kc = kbeg; kc < kend; kc += 32) {
        // stage A-tile 128x32 and B-tile 128x32 (16B per thread per tensor x2)
#pragma unroll
        for (int i = 0; i < 2; i++) {
            int idx = tid + i * 256;           // 0..511
            int r = idx >> 2, cq = idx & 3;
            uint4 va = *(const uint4*)(A + (long)(row0 + r) * K + kc + cq * 8);
            *(uint4*)(&As[r * 40 + cq * 8]) = va;
            uint4 vb = *(const uint4*)(Bt + (long)(col0 + r) * K + kc + cq * 8);
            *(uint4*)(&Bs[r * 40 + cq * 8]) = vb;
        }
        __syncthreads();
        bf16x8 af[4], bfr[4];
#pragma unroll
        for (int i = 0; i < 4; i++)
            af[i] = __builtin_bit_cast(bf16x8,
                *(const uint4*)(&As[(arow + i * 16 + l15) * 40 + quad * 8]));
#pragma unroll
        for (int j = 0; j < 4; j++)
            bfr[j] = __builtin_bit_cast(bf16x8,
                *(const uint4*)(&Bs[(bcol + j * 16 + l15) * 40 + quad * 8]));
#pragma unroll
        for (int i = 0; i < 4; i++)
#pragma unroll
            for (int j = 0; j < 4; j++)
                acc[i][j] = __builtin_amdgcn_mfma_f32_16x16x32_bf16(af[i], bfr[j], acc[i][j], 0, 0, 0);
        __syncthreads();
    }

    // epilogue: C/D layout col=lane&15, row=quad*4+reg  [m89/m91 verified]
#pragma unroll
    for (int i = 0; i < 4; i++)
#pragma unroll
        for (int j = 0; j < 4; j++) {
            int row = row0 + arow + i * 16 + quad * 4;
            int col = col0 + bcol + j * 16 + l15;
#pragma unroll
            for (int reg = 0; reg < 4; reg++) {
                float v = acc[i][j][reg];
                long o = (long)(row + reg) * HID + col;
                if (part) part[(long)blockIdx.z * M * HID + o] = v;
                else      outb[o] = f2bf(v);
            }
        }
}

// ---------------- reduce split-K partials + bias + lrelu -> bf16 ----------------
__global__ void k_reduce(const float* __restrict__ part, const float* __restrict__ bias,
                         uint16_t* __restrict__ out, int MN, int S) {
    int i = blockIdx.x * blockDim.x + threadIdx.x;
    if (i >= MN) return;
    float v = 0.f;
    for (int s = 0; s < S; s++) v += part[(long)s * MN + i];
    v += bias[i & (HID - 1)];
    v = v > 0.f ? v : NEG * v;
    out[i] = f2bf(v);
}

// ---------------- bf16 CSR gather-aggregate + bias + lrelu ----------------
// one wave per node; lane holds 4 bf16 (8B); fp32 accumulate; bf16 out
__global__ __launch_bounds__(256) void k_aggb(const uint16_t* __restrict__ hw,
                                              const float* __restrict__ dinv,
                                              const int* __restrict__ rowptr,
                                              const int* __restrict__ adj_src,
                                              const float* __restrict__ adj_w,
                                              const float* __restrict__ bias,
                                              uint16_t* __restrict__ out, int n) {
    __shared__ int ssrc[4][64];
    __shared__ float swt[4][64];
    int wv = threadIdx.x >> 6;
    int lane = threadIdx.x & 63;
    int node = blockIdx.x * 4 + wv;
    if (node >= n) return;
    const uint2* hw2 = (const uint2*)hw;
    float di = dinv[node];
    float c2 = di * di;
    uint2 h = hw2[(long)node * 64 + lane];
    float a0 = c2 * bf2f((uint16_t)(h.x & 0xffff));
    float a1 = c2 * bf2f((uint16_t)(h.x >> 16));
    float a2 = c2 * bf2f((uint16_t)(h.y & 0xffff));
    float a3 = c2 * bf2f((uint16_t)(h.y >> 16));
    int s = rowptr[node], e = rowptr[node + 1];
    for (int base = s; base < e; base += 64) {
        int m = e - base; if (m > 64) m = 64;
        if (lane < m) { ssrc[wv][lane] = adj_src[base + lane]; swt[wv][lane] = adj_w[base + lane]; }
        for (int t = 0; t < m; t++) {
            int src = ssrc[wv][t];
            float w = swt[wv][t];
            uint2 v = hw2[(long)src * 64 + lane];
            a0 += w * bf2f((uint16_t)(v.x & 0xffff));
            a1 += w * bf2f((uint16_t)(v.x >> 16));
            a2 += w * bf2f((uint16_t)(v.y & 0xffff));
            a3 += w * bf2f((uint16_t)(v.y >> 16));
        }
    }
    float4 b4 = ((const float4*)bias)[lane];
    a0 += b4.x; a1 += b4.y; a2 += b4.z; a3 += b4.w;
    a0 = a0 > 0.f ? a0 : NEG * a0;
    a1 = a1 > 0.f ? a1 : NEG * a1;
    a2 = a2 > 0.f ? a2 : NEG * a2;
    a3 = a3 > 0.f ? a3 : NEG * a3;
    uint2 o;
    o.x = (uint32_t)f2bf(a0) | ((uint32_t)f2bf(a1) << 16);
    o.y = (uint32_t)f2bf(a2) | ((uint32_t)f2bf(a3) << 16);
    ((uint2*)out)[(long)node * 64 + lane] = o;
}

// ---------------- build flat bf16 [Bn][FLATP] from h2, x64 ----------------
__global__ void k_flat(const uint16_t* __restrict__ h2, const uint16_t* __restrict__ x64,
                       uint16_t* __restrict__ flat, int Bn) {
    long total = (long)Bn * FLATP;
    for (long i = (long)blockIdx.x * blockDim.x + threadIdx.x; i < total;
         i += (long)gridDim.x * blockDim.x) {
        long b = i / FLATP;
        int gk = (int)(i - b * FLATP);
        uint16_t v = 0;
        if (gk < FLATK) {
            int m = gk / PERM;
            int k2 = gk - m * PERM;
            long node = b * MACH + m;
            v = (k2 < HID) ? h2[node * HID + k2] : x64[node * 64 + (k2 - HID)];
        }
        flat[i] = v;
    }
}

// ---------------- output layer ----------------
__global__ void k_out(const uint16_t* __restrict__ z2, const float* __restrict__ Wo,
                      const float* __restrict__ bo, void* out, const int* flags, int Bn) {
    int idx = blockIdx.x * blockDim.x + threadIdx.x;
    if (idx >= Bn * 4) return;
    int b = idx >> 2, o = idx & 3;
    float acc = bo[o];
    const uint16_t* zr = z2 + (long)b * HID;
    for (int k = 0; k < HID; k++) acc += bf2f(zr[k]) * Wo[k * 4 + o];
    if (flags[0]) ((uint16_t*)out)[idx] = f2bf(acc);
    else          ((float*)out)[idx] = acc;
}

// ---------------- host ----------------
extern "C" void kernel_launch(void* const* d_in, const int* in_sizes, int n_in,
                              void* d_out, int out_size, void* d_ws, size_t ws_size,
                              hipStream_t stream) {
    const int N  = in_sizes[0] / FEA;   // 45056
    const int E  = in_sizes[2];         // 720896
    const int Bn = N / MACH;            // 2048

    char* ws = (char*)d_ws;
    size_t off = 0;
    auto alloc = [&](size_t bytes) -> char* {
        char* p = ws + off;
        off = (off + bytes + 255) & ~(size_t)255;
        return p;
    };

    int*      flags  = (int*)     alloc(64);
    uint16_t* x64    = (uint16_t*)alloc((size_t)N * 64 * 2);
    float*    ew     = (float*)   alloc((size_t)E * 4);
    uint16_t* W1t    = (uint16_t*)alloc((size_t)HID * 64 * 2);
    uint16_t* W2t    = (uint16_t*)alloc((size_t)HID * HID * 2);
    uint16_t* Wf0t   = (uint16_t*)alloc((size_t)HID * FLATP * 2);
    uint16_t* Wf1t   = (uint16_t*)alloc((size_t)HID * HID * 2);
    uint16_t* Wf2t   = (uint16_t*)alloc((size_t)HID * HID * 2);
    float*    b1     = (float*)   alloc(HID * 4);
    float*    b2     = (float*)   alloc(HID * 4);
    float*    bf0    = (float*)   alloc(HID * 4);
    float*    bf1    = (float*)   alloc(HID * 4);
    float*    bf2    = (float*)   alloc(HID * 4);
    float*    Wo     = (float*)   alloc((size_t)HID * 4 * 4);
    float*    bo     = (float*)   alloc(4 * 4);
    int*      ei     = (int*)     alloc((size_t)2 * E * 4);
    float*    dinv   = (float*)   alloc((size_t)N * 4);
    int*      count  = (int*)     alloc((size_t)N * 4);
    int*      cursor = (int*)     alloc((size_t)N * 4);
    int*      rowptr = (int*)     alloc((size_t)(N + 1) * 4);
    int*      bsum   = (int*)     alloc(64 * 4);
    int*      boffs  = (int*)     alloc(64 * 4);
    int*      adj_src= (int*)     alloc((size_t)E * 4);
    float*    adj_w  = (float*)   alloc((size_t)E * 4);
    uint16_t* P      = (uint16_t*)alloc((size_t)N * HID * 2);  // hw buffer
    uint16_t* Q      = (uint16_t*)alloc((size_t)N * HID * 2);  // h1 / h2
    uint16_t* flat   = (uint16_t*)alloc((size_t)Bn * FLATP * 2);
    float*    part   = (float*)   alloc((size_t)8 * Bn * HID * 4);
    uint16_t* z0     = (uint16_t*)alloc((size_t)Bn * HID * 2);
    uint16_t* z1     = (uint16_t*)alloc((size_t)Bn * HID * 2);
    (void)ws_size; (void)n_in; (void)out_size;

    // 1. dtype detection
    k_detect<<<1, 256, 0, stream>>>((const uint32_t*)d_in[2], (const uint32_t*)d_in[1], flags);

    // 2. conversions
    Cvt8 c8{};
    const void* s8[8] = { d_in[2], d_in[4], d_in[6], d_in[8], d_in[10], d_in[12], d_in[13], d_in[14] };
    float* d8[8] = { ew, b1, b2, bf0, bf1, bf2, Wo, bo };
    long n8[8] = { E, HID, HID, HID, HID, HID, (long)HID * 4, 4 };
    c8.prefix[0] = 0;
    for (int t = 0; t < 8; t++) { c8.src[t] = s8[t]; c8.dst[t] = d8[t]; c8.prefix[t + 1] = c8.prefix[t] + n8[t]; }
    k_cvt_f32<<<1024, 256, 0, stream>>>(c8, flags);
    k_cvt_idx<<<2048, 256, 0, stream>>>(d_in[1], ei, (long)2 * E, flags);
    k_cvt_x<<<2048, 256, 0, stream>>>(d_in[0], x64, N, flags);
    k_transp<<<dim3(64 / 64, 4), 256, 0, stream>>>(d_in[3], W1t, FEA, 64, flags);
    k_transp<<<dim3(HID / 64, 4), 256, 0, stream>>>(d_in[5], W2t, HID, HID, flags);
    k_transp<<<dim3(FLATP / 64, 4), 256, 0, stream>>>(d_in[7], Wf0t, FLATK, FLATP, flags);
    k_transp<<<dim3(HID / 64, 4), 256, 0, stream>>>(d_in[9], Wf1t, HID, HID, flags);
    k_transp<<<dim3(HID / 64, 4), 256, 0, stream>>>(d_in[11], Wf2t, HID, HID, flags);

    // 3. degree + norm + CSR
    k_init<<<(N + 255) / 256, 256, 0, stream>>>(dinv, count, cursor, N);
    k_deg<<<(E + 255) / 256, 256, 0, stream>>>(ei, ew, dinv, count, E);
    k_dinv<<<(N + 255) / 256, 256, 0, stream>>>(dinv, N);
    int nb = (N + 1023) / 1024;          // 44
    k_scan1<<<nb, 1024, 0, stream>>>(count, rowptr, bsum, N);
    k_scan2<<<1, 1, 0, stream>>>(bsum, boffs, rowptr, nb, N);
    k_scan3<<<nb, 1024, 0, stream>>>(rowptr, boffs, N);
    k_fill<<<(E + 255) / 256, 256, 0, stream>>>(ei, ew, dinv, rowptr, cursor, adj_src, adj_w, E);

    // 4. GCN layer 1:  P = x64 @ W1t^T  (K=64) ; h1 = agg(P) -> Q
    k_mgemm<<<dim3(2, N / 128, 1), 256, 0, stream>>>(x64, W1t, nullptr, P, N, 64, 64);
    k_aggb<<<(N + 3) / 4, 256, 0, stream>>>(P, dinv, rowptr, adj_src, adj_w, b1, Q, N);

    // 5. GCN layer 2:  P = Q @ W2t^T (K=256) ; h2 = agg(P) -> Q
    k_mgemm<<<dim3(2, N / 128, 1), 256, 0, stream>>>(Q, W2t, nullptr, P, N, HID, HID);
    k_aggb<<<(N + 3) / 4, 256, 0, stream>>>(P, dinv, rowptr, adj_src, adj_w, b2, Q, N);

    // 6. flat build
    k_flat<<<4096, 256, 0, stream>>>(Q, x64, flat, Bn);

    // 7. mlp0: split-K S=8, Kc=896 (28*32)
    k_mgemm<<<dim3(2, Bn / 128, 8), 256, 0, stream>>>(flat, Wf0t, part, nullptr, Bn, FLATP, 896);
    k_reduce<<<(Bn * HID + 255) / 256, 256, 0, stream>>>(part, bf0, z0, Bn * HID, 8);

    // 8. mlp1: S=4, Kc=64
    k_mgemm<<<dim3(2, Bn / 128, 4), 256, 0, stream>>>(z0, Wf1t, part, nullptr, Bn, HID, 64);
    k_reduce<<<(Bn * HID + 255) / 256, 256, 0, stream>>>(part, bf1, z1, Bn * HID, 4);

    // 9. mlp2: S=4, Kc=64
    k_mgemm<<<dim3(2, Bn / 128, 4), 256, 0, stream>>>(z1, Wf2t, part, nullptr, Bn, HID, 64);
    k_reduce<<<(Bn * HID + 255) / 256, 256, 0, stream>>>(part, bf2, z0, Bn * HID, 4);

    // 10. output
    k_out<<<(Bn * 4 + 255) / 256, 256, 0, stream>>>(z0, Wo, bo, d_out, flags, Bn);
}

// Round 4
// 374.162 us; speedup vs baseline: 4.2720x; 1.2951x over previous
//
#include <hip/hip_runtime.h>
#include <stdint.h>

#define FEA 60
#define HID 256
#define MACH 22
#define PERM 316             // HID + FEA (reference layout)
#define PERM2 320            // padded per-machine stride (mult of 8: no uint4 straddle)
#define FLATP2 (MACH * PERM2)   // 7040 = 11*640, mult of 32
#define NEG 0.01f

typedef __bf16 bf16x8 __attribute__((ext_vector_type(8)));
typedef float f32x4 __attribute__((ext_vector_type(4)));

__device__ __forceinline__ float bf2f(uint16_t u) {
    return __uint_as_float(((uint32_t)u) << 16);
}
__device__ __forceinline__ uint16_t f2bf(float f) {   // RNE
    uint32_t x = __float_as_uint(f);
    return (uint16_t)((x + 0x7fffu + ((x >> 16) & 1u)) >> 16);
}
__device__ __forceinline__ int load_idx(const void* p, long i, int i64) {
    return i64 ? (int)((const long long*)p)[i] : ((const int*)p)[i];
}
__device__ __forceinline__ float load_w(const void* p, long i, int isbf) {
    return isbf ? bf2f(((const uint16_t*)p)[i]) : ((const float*)p)[i];
}

// ---------------- dtype detection ----------------
__global__ void k_detect(const uint32_t* ew_w, const uint32_t* ei_w, int* flags) {
    __shared__ int c15, onz;
    if (threadIdx.x == 0) { c15 = 0; onz = 0; }
    __syncthreads();
    int a = 0, b = 0;
    for (int i = threadIdx.x; i < 1024; i += 256) {
        if (ew_w[i] & 0x8000u) a++;
        if (ei_w[2 * i + 1] != 0u) b++;
    }
    atomicAdd(&c15, a); atomicAdd(&onz, b);
    __syncthreads();
    if (threadIdx.x == 0) {
        flags[0] = (c15 <= 100) ? 1 : 0;
        flags[1] = (onz < 8) ? 1 : 0;
    }
}

// ---------------- small fp32 conversions ----------------
struct Cvt8 {
    const void* src[8];
    float* dst[8];
    long prefix[9];
    int cnt;
};

__global__ void k_cvt_f32(Cvt8 a, const int* flags) {
    int isbf = flags[0];
    long total = a.prefix[a.cnt];
    for (long i = (long)blockIdx.x * blockDim.x + threadIdx.x; i < total;
         i += (long)gridDim.x * blockDim.x) {
        int t = 0;
        while (i >= a.prefix[t + 1]) t++;
        long j = i - a.prefix[t];
        a.dst[t][j] = isbf ? bf2f(((const uint16_t*)a.src[t])[j])
                           : ((const float*)a.src[t])[j];
    }
}

// x [N][60] -> x64 bf16 [N][64], cols 60..63 = 0
__global__ void k_cvt_x(const void* src, uint16_t* dst, int n, const int* flags) {
    int isbf = flags[0];
    long total = (long)n * 64;
    for (long i = (long)blockIdx.x * blockDim.x + threadIdx.x; i < total;
         i += (long)gridDim.x * blockDim.x) {
        int col = (int)(i & 63);
        long row = i >> 6;
        uint16_t v = 0;
        if (col < FEA) {
            long s = row * FEA + col;
            v = isbf ? ((const uint16_t*)src)[s] : f2bf(((const float*)src)[s]);
        }
        dst[i] = v;
    }
}

// W [K][256] -> Wt bf16 [256][Kpad], zero-fill k>=K. Grid (Kpad/64, 4), 256 thr.
__global__ void k_transp(const void* W, uint16_t* Wt, int K, int Kpad, const int* flags) {
    __shared__ uint16_t s[64][65];
    int isbf = flags[0];
    int k0 = blockIdx.x * 64, n0 = blockIdx.y * 64;
    int t = threadIdx.x;
#pragma unroll
    for (int i = 0; i < 16; i++) {
        int idx = t + i * 256;
        int kk = idx >> 6, nn = idx & 63;
        int k = k0 + kk;
        uint16_t v = 0;
        if (k < K) {
            long off = (long)k * HID + n0 + nn;
            v = isbf ? ((const uint16_t*)W)[off] : f2bf(((const float*)W)[off]);
        }
        s[kk][nn] = v;
    }
    __syncthreads();
#pragma unroll
    for (int i = 0; i < 16; i++) {
        int idx = t + i * 256;
        int nn = idx >> 6, kk = idx & 63;
        Wt[(long)(n0 + nn) * Kpad + k0 + kk] = s[kk][nn];
    }
}

// Wf0 [6952][256] -> Wf0t bf16 [256][7040] with padded per-machine stride 320.
// gk = m*320 + k2 ; source k = m*316 + k2 (k2<316), zero else.
__global__ void k_transp_wf0(const void* W, uint16_t* Wt, const int* flags) {
    __shared__ uint16_t s[64][65];
    int isbf = flags[0];
    int g0 = blockIdx.x * 64, n0 = blockIdx.y * 64;
    int t = threadIdx.x;
#pragma unroll
    for (int i = 0; i < 16; i++) {
        int idx = t + i * 256;
        int gg = idx >> 6, nn = idx & 63;
        int gk = g0 + gg;
        int m = gk / PERM2;
        int k2 = gk - m * PERM2;
        uint16_t v = 0;
        if (k2 < PERM) {
            long off = (long)(m * PERM + k2) * HID + n0 + nn;
            v = isbf ? ((const uint16_t*)W)[off] : f2bf(((const float*)W)[off]);
        }
        s[gg][nn] = v;
    }
    __syncthreads();
#pragma unroll
    for (int i = 0; i < 16; i++) {
        int idx = t + i * 256;
        int nn = idx >> 6, gg = idx & 63;
        Wt[(long)(n0 + nn) * FLATP2 + g0 + gg] = s[gg][nn];
    }
}

// ---------------- CSR build: ONE atomic pass ----------------
__global__ void k_init(int* count, int n) {
    int i = blockIdx.x * blockDim.x + threadIdx.x;
    if (i < n) count[i] = 0;
}

__global__ void k_count(const void* ei, int E, int* count, int* rank, const int* flags) {
    int e = blockIdx.x * blockDim.x + threadIdx.x;
    if (e >= E) return;
    int c = load_idx(ei, (long)E + e, flags[1]);
    rank[e] = atomicAdd(&count[c], 1);
}

// hierarchical exclusive scan ; 44 blocks x 1024
__global__ void k_scan1(const int* count, int* rowptr, int* bsum, int n) {
    __shared__ int sd[1024];
    int i = blockIdx.x * 1024 + threadIdx.x;
    int v = (i < n) ? count[i] : 0;
    sd[threadIdx.x] = v;
    __syncthreads();
    for (int off = 1; off < 1024; off <<= 1) {
        int t = (threadIdx.x >= (unsigned)off) ? sd[threadIdx.x - off] : 0;
        __syncthreads();
        sd[threadIdx.x] += t;
        __syncthreads();
    }
    if (i < n) rowptr[i] = sd[threadIdx.x] - v;
    if (threadIdx.x == 1023) bsum[blockIdx.x] = sd[1023];
}

__global__ void k_scan2(int* bsum, int* boffs, int* rowptr, int nb, int n) {
    int acc = 0;
    for (int i = 0; i < nb; i++) { boffs[i] = acc; acc += bsum[i]; }
    rowptr[n] = acc;
}

__global__ void k_scan3(int* rowptr, const int* boffs, int n) {
    int i = blockIdx.x * 1024 + threadIdx.x;
    if (i < n) rowptr[i] += boffs[blockIdx.x];
}

// fill CSR, no atomics: pos = rowptr[c] + rank[e]; stores RAW ew
__global__ void k_fill(const void* ei, const void* ew, const int* rowptr, const int* rank,
                       int* adj_src, float* adj_w, int E, const int* flags) {
    int e = blockIdx.x * blockDim.x + threadIdx.x;
    if (e >= E) return;
    int i64 = flags[1];
    int r = load_idx(ei, e, i64);
    int c = load_idx(ei, (long)E + e, i64);
    float w = load_w(ew, e, flags[0]);
    int pos = rowptr[c] + rank[e];
    adj_src[pos] = r;
    adj_w[pos] = w;
}

// deg[i] = 1 + row-sum of raw ew ; dinv = 1/sqrt(deg)  (contiguous, no atomics)
__global__ void k_rowsum(const int* rowptr, const float* adj_w, float* dinv, int n) {
    int i = blockIdx.x * blockDim.x + threadIdx.x;
    if (i >= n) return;
    int s = rowptr[i], e = rowptr[i + 1];
    double d = 1.0;
    for (int p = s; p < e; p++) d += (double)adj_w[p];
    dinv[i] = (float)(1.0 / sqrt(d));
}

// ---------------- layer-1 pre-aggregation on x64 [N][64] ----------------
// xa[c] = dinv[c]^2 * x64[c] + sum ew*dinv[src]*dinv[c]*x64[src]
// half-wave (32 lanes) per node; lane reads uint (2 bf16 cols)
__global__ __launch_bounds__(256) void k_aggx(const uint16_t* __restrict__ x64,
                                              const float* __restrict__ dinv,
                                              const int* __restrict__ rowptr,
                                              const int* __restrict__ adj_src,
                                              const float* __restrict__ adj_w,
                                              uint16_t* __restrict__ xa, int n) {
    __shared__ int ssrc[8][32];
    __shared__ float swt[8][32];
    int hwv = threadIdx.x >> 5;
    int l32 = threadIdx.x & 31;
    int node = blockIdx.x * 8 + hwv;
    if (node >= n) return;
    const uint32_t* xu = (const uint32_t*)x64;
    float di = dinv[node];
    float c2 = di * di;
    uint32_t h = xu[(long)node * 32 + l32];
    float a0 = c2 * bf2f((uint16_t)(h & 0xffff));
    float a1 = c2 * bf2f((uint16_t)(h >> 16));
    int s = rowptr[node], e = rowptr[node + 1];
    for (int base = s; base < e; base += 32) {
        int m = e - base; if (m > 32) m = 32;
        if (l32 < m) {
            int s0 = adj_src[base + l32];
            ssrc[hwv][l32] = s0;
            swt[hwv][l32] = adj_w[base + l32] * dinv[s0] * di;
        }
        for (int t = 0; t < m; t++) {
            int src = ssrc[hwv][t];
            float w = swt[hwv][t];
            uint32_t v = xu[(long)src * 32 + l32];
            a0 += w * bf2f((uint16_t)(v & 0xffff));
            a1 += w * bf2f((uint16_t)(v >> 16));
        }
    }
    ((uint32_t*)xa)[(long)node * 32 + l32] =
        (uint32_t)f2bf(a0) | ((uint32_t)f2bf(a1) << 16);
}

// ---------------- bf16 CSR gather-aggregate (256 cols) + bias + lrelu ----------------
__global__ __launch_bounds__(256) void k_aggb(const uint16_t* __restrict__ hw,
                                              const float* __restrict__ dinv,
                                              const int* __restrict__ rowptr,
                                              const int* __restrict__ adj_src,
                                              const float* __restrict__ adj_w,
                                              const float* __restrict__ bias,
                                              uint16_t* __restrict__ out, int n) {
    __shared__ int ssrc[4][64];
    __shared__ float swt[4][64];
    int wv = threadIdx.x >> 6;
    int lane = threadIdx.x & 63;
    int node = blockIdx.x * 4 + wv;
    if (node >= n) return;
    const uint2* hw2 = (const uint2*)hw;
    float di = dinv[node];
    float c2 = di * di;
    uint2 h = hw2[(long)node * 64 + lane];
    float a0 = c2 * bf2f((uint16_t)(h.x & 0xffff));
    float a1 = c2 * bf2f((uint16_t)(h.x >> 16));
    float a2 = c2 * bf2f((uint16_t)(h.y & 0xffff));
    float a3 = c2 * bf2f((uint16_t)(h.y >> 16));
    int s = rowptr[node], e = rowptr[node + 1];
    for (int base = s; base < e; base += 64) {
        int m = e - base; if (m > 64) m = 64;
        if (lane < m) {
            int s0 = adj_src[base + lane];
            ssrc[wv][lane] = s0;
            swt[wv][lane] = adj_w[base + lane] * dinv[s0] * di;
        }
        for (int t = 0; t < m; t++) {
            int src = ssrc[wv][t];
            float w = swt[wv][t];
            uint2 v = hw2[(long)src * 64 + lane];
            a0 += w * bf2f((uint16_t)(v.x & 0xffff));
            a1 += w * bf2f((uint16_t)(v.x >> 16));
            a2 += w * bf2f((uint16_t)(v.y & 0xffff));
            a3 += w * bf2f((uint16_t)(v.y >> 16));
        }
    }
    float4 b4 = ((const float4*)bias)[lane];
    a0 += b4.x; a1 += b4.y; a2 += b4.z; a3 += b4.w;
    a0 = a0 > 0.f ? a0 : NEG * a0;
    a1 = a1 > 0.f ? a1 : NEG * a1;
    a2 = a2 > 0.f ? a2 : NEG * a2;
    a3 = a3 > 0.f ? a3 : NEG * a3;
    uint2 o;
    o.x = (uint32_t)f2bf(a0) | ((uint32_t)f2bf(a1) << 16);
    o.y = (uint32_t)f2bf(a2) | ((uint32_t)f2bf(a3) << 16);
    ((uint2*)out)[(long)node * 64 + lane] = o;
}

// ---------------- bf16 MFMA GEMM (plain A) ----------------
// C[M,256] = A[M][K] @ Bt[256][K]^T. Tile 128x128, 4 waves x 64x64.
// part!=0: fp32 partials (split-K). Else bf16 out with optional bias+lrelu.
__global__ __launch_bounds__(256) void k_mgemm(const uint16_t* __restrict__ A,
                                               const uint16_t* __restrict__ Bt,
                                               float* __restrict__ part,
                                               uint16_t* __restrict__ outb,
                                               const float* __restrict__ bias,
                                               int M, int K, int Kc, int act) {
    __shared__ uint16_t As[128 * 40];
    __shared__ uint16_t Bs[128 * 40];
    int tid = threadIdx.x;
    int lane = tid & 63, wv = tid >> 6;
    int quad = lane >> 4, l15 = lane & 15;
    int row0 = blockIdx.y * 128, col0 = blockIdx.x * 128;
    int kbeg = blockIdx.z * Kc;
    int kend = kbeg + Kc; if (kend > K) kend = K;
    int arow = (wv >> 1) * 64;
    int bcol = (wv & 1) * 64;

    f32x4 acc[4][4];
#pragma unroll
    for (int i = 0; i < 4; i++)
#pragma unroll
        for (int j = 0; j < 4; j++) acc[i][j] = (f32x4){0.f, 0.f, 0.f, 0.f};

    for (int kc = kbeg; kc < kend; kc += 32) {
#pragma unroll
        for (int i = 0; i < 2; i++) {
            int idx = tid + i * 256;
            int r = idx >> 2, cq = idx & 3;
            uint4 va = *(const uint4*)(A + (long)(row0 + r) * K + kc + cq * 8);
            *(uint4*)(&As[r * 40 + cq * 8]) = va;
            uint4 vb = *(const uint4*)(Bt + (long)(col0 + r) * K + kc + cq * 8);
            *(uint4*)(&Bs[r * 40 + cq * 8]) = vb;
        }
        __syncthreads();
        bf16x8 af[4], bfr[4];
#pragma unroll
        for (int i = 0; i < 4; i++)
            af[i] = __builtin_bit_cast(bf16x8,
                *(const uint4*)(&As[(arow + i * 16 + l15) * 40 + quad * 8]));
#pragma unroll
        for (int j = 0; j < 4; j++)
            bfr[j] = __builtin_bit_cast(bf16x8,
                *(const uint4*)(&Bs[(bcol + j * 16 + l15) * 40 + quad * 8]));
#pragma unroll
        for (int i = 0; i < 4; i++)
#pragma unroll
            for (int j = 0; j < 4; j++)
                acc[i][j] = __builtin_amdgcn_mfma_f32_16x16x32_bf16(af[i], bfr[j], acc[i][j], 0, 0, 0);
        __syncthreads();
    }

#pragma unroll
    for (int i = 0; i < 4; i++)
#pragma unroll
        for (int j = 0; j < 4; j++) {
            int row = row0 + arow + i * 16 + quad * 4;
            int col = col0 + bcol + j * 16 + l15;
#pragma unroll
            for (int reg = 0; reg < 4; reg++) {
                float v = acc[i][j][reg];
                long o = (long)(row + reg) * HID + col;
                if (part) part[(long)blockIdx.z * M * HID + o] = v;
                else {
                    if (bias) v += bias[col];
                    if (act) v = v > 0.f ? v : NEG * v;
                    outb[o] = f2bf(v);
                }
            }
        }
}

// ---------------- bf16 MFMA GEMM with VIRTUAL flat A (mlp0) ----------------
// A[b][gk]: m=gk/320, k2=gk%320 ; k2<256 -> h2[node][k2] ; else x64[node][k2-256]
__global__ __launch_bounds__(256) void k_mgemm_flat(const uint16_t* __restrict__ h2,
                                                    const uint16_t* __restrict__ x64,
                                                    const uint16_t* __restrict__ Bt,
                                                    float* __restrict__ part,
                                                    int M, int Kc) {
    __shared__ uint16_t As[128 * 40];
    __shared__ uint16_t Bs[128 * 40];
    int tid = threadIdx.x;
    int lane = tid & 63, wv = tid >> 6;
    int quad = lane >> 4, l15 = lane & 15;
    int row0 = blockIdx.y * 128, col0 = blockIdx.x * 128;
    int kbeg = blockIdx.z * Kc;
    int kend = kbeg + Kc;
    int arow = (wv >> 1) * 64;
    int bcol = (wv & 1) * 64;

    f32x4 acc[4][4];
#pragma unroll
    for (int i = 0; i < 4; i++)
#pragma unroll
        for (int j = 0; j < 4; j++) acc[i][j] = (f32x4){0.f, 0.f, 0.f, 0.f};

    for (int kc = kbeg; kc < kend; kc += 32) {
#pragma unroll
        for (int i = 0; i < 2; i++) {
            int idx = tid + i * 256;
            int r = idx >> 2, cq = idx & 3;
            int gk = kc + cq * 8;
            int m = gk / PERM2;
            int k2 = gk - m * PERM2;
            long node = (long)(row0 + r) * MACH + m;
            uint4 va = (k2 < HID)
                ? *(const uint4*)(h2 + node * HID + k2)
                : *(const uint4*)(x64 + node * 64 + (k2 - HID));
            *(uint4*)(&As[r * 40 + cq * 8]) = va;
            uint4 vb = *(const uint4*)(Bt + (long)(col0 + r) * FLATP2 + gk);
            *(uint4*)(&Bs[r * 40 + cq * 8]) = vb;
        }
        __syncthreads();
        bf16x8 af[4], bfr[4];
#pragma unroll
        for (int i = 0; i < 4; i++)
            af[i] = __builtin_bit_cast(bf16x8,
                *(const uint4*)(&As[(arow + i * 16 + l15) * 40 + quad * 8]));
#pragma unroll
        for (int j = 0; j < 4; j++)
            bfr[j] = __builtin_bit_cast(bf16x8,
                *(const uint4*)(&Bs[(bcol + j * 16 + l15) * 40 + quad * 8]));
#pragma unroll
        for (int i = 0; i < 4; i++)
#pragma unroll
            for (int j = 0; j < 4; j++)
                acc[i][j] = __builtin_amdgcn_mfma_f32_16x16x32_bf16(af[i], bfr[j], acc[i][j], 0, 0, 0);
        __syncthreads();
    }

#pragma unroll
    for (int i = 0; i < 4; i++)
#pragma unroll
        for (int j = 0; j < 4; j++) {
            int row = row0 + arow + i * 16 + quad * 4;
            int col = col0 + bcol + j * 16 + l15;
#pragma unroll
            for (int reg = 0; reg < 4; reg++)
                part[(long)blockIdx.z * M * HID + (long)(row + reg) * HID + col] = acc[i][j][reg];
        }
}

// ---------------- reduce split-K partials + bias + lrelu -> bf16 ----------------
__global__ void k_reduce(const float* __restrict__ part, const float* __restrict__ bias,
                         uint16_t* __restrict__ out, int MN, int S) {
    int i = blockIdx.x * blockDim.x + threadIdx.x;
    if (i >= MN) return;
    float v = 0.f;
    for (int s = 0; s < S; s++) v += part[(long)s * MN + i];
    v += bias[i & (HID - 1)];
    v = v > 0.f ? v : NEG * v;
    out[i] = f2bf(v);
}

// ---------------- fused MLP tail: z0 -> mlp1 -> mlp2 -> out ----------------
// 128 blocks x 256 thr; block = 16 batch rows. Weights from L2, z via LDS.
__global__ __launch_bounds__(256) void k_tail(const uint16_t* __restrict__ z0,
                                              const uint16_t* __restrict__ Wf1t,
                                              const float* __restrict__ bf1,
                                              const uint16_t* __restrict__ Wf2t,
                                              const float* __restrict__ bf2,
                                              const float* __restrict__ Wo,
                                              const float* __restrict__ bo,
                                              void* out, const int* flags) {
    __shared__ uint16_t z1s[16 * 256];
    __shared__ uint16_t z2s[16 * 256];
    int tid = threadIdx.x;
    int lane = tid & 63, wv = tid >> 6;
    int quad = lane >> 4, l15 = lane & 15;
    int rows0 = blockIdx.x * 16;
    int nw = wv * 64;

    // layer 1: z1 = lrelu(z0 @ Wf1t^T + bf1)
    {
        f32x4 acc[4];
#pragma unroll
        for (int j = 0; j < 4; j++) acc[j] = (f32x4){0.f, 0.f, 0.f, 0.f};
        for (int kc = 0; kc < HID; kc += 32) {
            bf16x8 a = __builtin_bit_cast(bf16x8,
                *(const uint4*)(z0 + (long)(rows0 + l15) * HID + kc + quad * 8));
#pragma unroll
            for (int j = 0; j < 4; j++) {
                bf16x8 b = __builtin_bit_cast(bf16x8,
                    *(const uint4*)(Wf1t + (long)(nw + j * 16 + l15) * HID + kc + quad * 8));
                acc[j] = __builtin_amdgcn_mfma_f32_16x16x32_bf16(a, b, acc[j], 0, 0, 0);
            }
        }
#pragma unroll
        for (int j = 0; j < 4; j++) {
            int col = nw + j * 16 + l15;
            float bj = bf1[col];
#pragma unroll
            for (int reg = 0; reg < 4; reg++) {
                float v = acc[j][reg] + bj;
                v = v > 0.f ? v : NEG * v;
                z1s[(quad * 4 + reg) * 256 + col] = f2bf(v);
            }
        }
    }
    __syncthreads();

    // layer 2: z2 = lrelu(z1 @ Wf2t^T + bf2)
    {
        f32x4 acc[4];
#pragma unroll
        for (int j = 0; j < 4; j++) acc[j] = (f32x4){0.f, 0.f, 0.f, 0.f};
        for (int kc = 0; kc < HID; kc += 32) {
            bf16x8 a = __builtin_bit_cast(bf16x8,
                *(const uint4*)(&z1s[l15 * 256 + kc + quad * 8]));
#pragma unroll
            for (int j = 0; j < 4; j++) {
                bf16x8 b = __builtin_bit_cast(bf16x8,
                    *(const uint4*)(Wf2t + (long)(nw + j * 16 + l15) * HID + kc + quad * 8));
                acc[j] = __builtin_amdgcn_mfma_f32_16x16x32_bf16(a, b, acc[j], 0, 0, 0);
            }
        }
#pragma unroll
        for (int j = 0; j < 4; j++) {
            int col = nw + j * 16 + l15;
            float bj = bf2[col];
#pragma unroll
            for (int reg = 0; reg < 4; reg++) {
                float v = acc[j][reg] + bj;
                v = v > 0.f ? v : NEG * v;
                z2s[(quad * 4 + reg) * 256 + col] = f2bf(v);
            }
        }
    }
    __syncthreads();

    // output: out[r][o] = z2[r] . Wo[:,o] + bo[o]
    if (tid < 64) {
        int r = tid >> 2, o = tid & 3;
        float acc = bo[o];
        for (int k = 0; k < HID; k++)
            acc += bf2f(z2s[r * 256 + k]) * Wo[k * 4 + o];
        long idx = (long)(rows0 + r) * 4 + o;
        if (flags[0]) ((uint16_t*)out)[idx] = f2bf(acc);
        else          ((float*)out)[idx] = acc;
    }
}

// ---------------- host ----------------
extern "C" void kernel_launch(void* const* d_in, const int* in_sizes, int n_in,
                              void* d_out, int out_size, void* d_ws, size_t ws_size,
                              hipStream_t stream) {
    const int N  = in_sizes[0] / FEA;   // 45056
    const int E  = in_sizes[2];         // 720896
    const int Bn = N / MACH;            // 2048
    const int S0 = 11, Kc0 = FLATP2 / 11;  // 640, mult of 32

    char* ws = (char*)d_ws;
    size_t off = 0;
    auto alloc = [&](size_t bytes) -> char* {
        char* p = ws + off;
        off = (off + bytes + 255) & ~(size_t)255;
        return p;
    };

    int*      flags  = (int*)     alloc(64);
    uint16_t* x64    = (uint16_t*)alloc((size_t)N * 64 * 2);
    uint16_t* xa     = (uint16_t*)alloc((size_t)N * 64 * 2);
    uint16_t* W1t    = (uint16_t*)alloc((size_t)HID * 64 * 2);
    uint16_t* W2t    = (uint16_t*)alloc((size_t)HID * HID * 2);
    uint16_t* Wf0t   = (uint16_t*)alloc((size_t)HID * FLATP2 * 2);
    uint16_t* Wf1t   = (uint16_t*)alloc((size_t)HID * HID * 2);
    uint16_t* Wf2t   = (uint16_t*)alloc((size_t)HID * HID * 2);
    float*    b1     = (float*)   alloc(HID * 4);
    float*    b2     = (float*)   alloc(HID * 4);
    float*    bf0    = (float*)   alloc(HID * 4);
    float*    bf1    = (float*)   alloc(HID * 4);
    float*    bf2    = (float*)   alloc(HID * 4);
    float*    Wo     = (float*)   alloc((size_t)HID * 4 * 4);
    float*    bo     = (float*)   alloc(4 * 4);
    int*      count  = (int*)     alloc((size_t)N * 4);
    int*      rank   = (int*)     alloc((size_t)E * 4);
    int*      rowptr = (int*)     alloc((size_t)(N + 1) * 4);
    int*      bsum   = (int*)     alloc(64 * 4);
    int*      boffs  = (int*)     alloc(64 * 4);
    int*      adj_src= (int*)     alloc((size_t)E * 4);
    float*    adj_w  = (float*)   alloc((size_t)E * 4);
    float*    dinv   = (float*)   alloc((size_t)N * 4);
    uint16_t* P      = (uint16_t*)alloc((size_t)N * HID * 2);  // hw / h1
    uint16_t* Q      = (uint16_t*)alloc((size_t)N * HID * 2);  // h2
    float*    part   = (float*)   alloc((size_t)S0 * Bn * HID * 4);
    uint16_t* z0     = (uint16_t*)alloc((size_t)Bn * HID * 2);
    (void)ws_size; (void)n_in; (void)out_size;

    // 1. dtype detection
    k_detect<<<1, 256, 0, stream>>>((const uint32_t*)d_in[2], (const uint32_t*)d_in[1], flags);

    // 2. conversions / transposes
    Cvt8 c8{};
    const void* s8[7] = { d_in[4], d_in[6], d_in[8], d_in[10], d_in[12], d_in[13], d_in[14] };
    float* d8[7] = { b1, b2, bf0, bf1, bf2, Wo, bo };
    long n8[7] = { HID, HID, HID, HID, HID, (long)HID * 4, 4 };
    c8.cnt = 7;
    c8.prefix[0] = 0;
    for (int t = 0; t < 7; t++) { c8.src[t] = s8[t]; c8.dst[t] = d8[t]; c8.prefix[t + 1] = c8.prefix[t] + n8[t]; }
    c8.prefix[8] = c8.prefix[7];
    k_cvt_f32<<<64, 256, 0, stream>>>(c8, flags);
    k_cvt_x<<<2048, 256, 0, stream>>>(d_in[0], x64, N, flags);
    k_transp<<<dim3(1, 4), 256, 0, stream>>>(d_in[3], W1t, FEA, 64, flags);
    k_transp<<<dim3(4, 4), 256, 0, stream>>>(d_in[5], W2t, HID, HID, flags);
    k_transp_wf0<<<dim3(FLATP2 / 64, 4), 256, 0, stream>>>(d_in[7], Wf0t, flags);
    k_transp<<<dim3(4, 4), 256, 0, stream>>>(d_in[9], Wf1t, HID, HID, flags);
    k_transp<<<dim3(4, 4), 256, 0, stream>>>(d_in[11], Wf2t, HID, HID, flags);

    // 3. CSR (one atomic pass) + degree from CSR
    k_init<<<(N + 255) / 256, 256, 0, stream>>>(count, N);
    k_count<<<(E + 255) / 256, 256, 0, stream>>>(d_in[1], E, count, rank, flags);
    int nb = (N + 1023) / 1024;          // 44
    k_scan1<<<nb, 1024, 0, stream>>>(count, rowptr, bsum, N);
    k_scan2<<<1, 1, 0, stream>>>(bsum, boffs, rowptr, nb, N);
    k_scan3<<<nb, 1024, 0, stream>>>(rowptr, boffs, N);
    k_fill<<<(E + 255) / 256, 256, 0, stream>>>(d_in[1], d_in[2], rowptr, rank, adj_src, adj_w, E, flags);
    k_rowsum<<<(N + 255) / 256, 256, 0, stream>>>(rowptr, adj_w, dinv, N);

    // 4. GCN layer 1: xa = agg(x64) ; h1 = lrelu(xa @ W1t + b1)   [agg-first]
    k_aggx<<<(N + 7) / 8, 256, 0, stream>>>(x64, dinv, rowptr, adj_src, adj_w, xa, N);
    k_mgemm<<<dim3(2, N / 128, 1), 256, 0, stream>>>(xa, W1t, nullptr, P, b1, N, 64, 64, 1);

    // 5. GCN layer 2: hw = h1 @ W2t ; h2 = agg(hw) + b2, lrelu
    k_mgemm<<<dim3(2, N / 128, 1), 256, 0, stream>>>(P, W2t, nullptr, Q, nullptr, N, HID, HID, 0);
    k_aggb<<<(N + 3) / 4, 256, 0, stream>>>(Q, dinv, rowptr, adj_src, adj_w, b2, P, N);

    // 6. mlp0: virtual-flat split-K (S=11, Kc=640)
    k_mgemm_flat<<<dim3(2, Bn / 128, S0), 256, 0, stream>>>(P, x64, Wf0t, part, Bn, Kc0);
    k_reduce<<<(Bn * HID + 255) / 256, 256, 0, stream>>>(part, bf0, z0, Bn * HID, S0);

    // 7. fused tail: mlp1 -> mlp2 -> out
    k_tail<<<Bn / 16, 256, 0, stream>>>(z0, Wf1t, bf1, Wf2t, bf2, Wo, bo, d_out, flags);
}

// Round 5
// 344.122 us; speedup vs baseline: 4.6450x; 1.0873x over previous
//
#include <hip/hip_runtime.h>
#include <stdint.h>

#define FEA 60
#define HID 256
#define MACH 22
#define PERM 316             // HID + FEA (reference layout)
#define PERM2 320            // padded per-machine stride (mult of 8)
#define FLATP2 (MACH * PERM2)   // 7040
#define NEG 0.01f

typedef __bf16 bf16x8 __attribute__((ext_vector_type(8)));
typedef float f32x4 __attribute__((ext_vector_type(4)));

__device__ __forceinline__ float bf2f(uint16_t u) {
    return __uint_as_float(((uint32_t)u) << 16);
}
__device__ __forceinline__ uint16_t f2bf(float f) {   // RNE
    uint32_t x = __float_as_uint(f);
    return (uint16_t)((x + 0x7fffu + ((x >> 16) & 1u)) >> 16);
}

// ---------------- detect dtypes + zero count ----------------
// flags[0]=1 if float tensors bf16 ; flags[1]=1 if edge_index int64
__global__ void k_detect_init(const uint32_t* ew_w, const uint32_t* ei_w, int* flags,
                              int* count, int n) {
    int i = blockIdx.x * blockDim.x + threadIdx.x;
    if (i < n) count[i] = 0;
    if (blockIdx.x == 0) {
        __shared__ int c15, onz;
        if (threadIdx.x == 0) { c15 = 0; onz = 0; }
        __syncthreads();
        int a = 0, b = 0;
        for (int k = threadIdx.x; k < 1024; k += 256) {
            if (ew_w[k] & 0x8000u) a++;
            if (ei_w[2 * k + 1] != 0u) b++;
        }
        atomicAdd(&c15, a); atomicAdd(&onz, b);
        __syncthreads();
        if (threadIdx.x == 0) {
            flags[0] = (c15 <= 100) ? 1 : 0;
            flags[1] = (onz < 8) ? 1 : 0;
        }
    }
}

// ---------------- conversions: x64 + small fp32 tensors, one kernel ----------------
struct Cvt8 {
    const void* src[8];
    float* dst[8];
    long prefix[9];
    int cnt;
};

__global__ void k_cvt_all(const void* xsrc, uint16_t* x64, int n, Cvt8 a, const int* flags) {
    int isbf = flags[0];
    long nx = (long)n * 64;
    long total = nx + a.prefix[a.cnt];
    for (long i = (long)blockIdx.x * blockDim.x + threadIdx.x; i < total;
         i += (long)gridDim.x * blockDim.x) {
        if (i < nx) {
            int col = (int)(i & 63);
            long row = i >> 6;
            uint16_t v = 0;
            if (col < FEA) {
                long s = row * FEA + col;
                v = isbf ? ((const uint16_t*)xsrc)[s] : f2bf(((const float*)xsrc)[s]);
            }
            x64[i] = v;
        } else {
            long ii = i - nx;
            int t = 0;
            while (ii >= a.prefix[t + 1]) t++;
            long j = ii - a.prefix[t];
            a.dst[t][j] = isbf ? bf2f(((const uint16_t*)a.src[t])[j])
                               : ((const float*)a.src[t])[j];
        }
    }
}

// ---------------- transposes ----------------
// W [K][256] -> Wt bf16 [256][Kpad]; grid (Kpad/64, 4[, nz])
__global__ void k_transp(const void* W, uint16_t* Wt, int K, int Kpad, const int* flags) {
    __shared__ uint16_t s[64][65];
    int isbf = flags[0];
    int k0 = blockIdx.x * 64, n0 = blockIdx.y * 64;
    int t = threadIdx.x;
#pragma unroll
    for (int i = 0; i < 16; i++) {
        int idx = t + i * 256;
        int kk = idx >> 6, nn = idx & 63;
        int k = k0 + kk;
        uint16_t v = 0;
        if (k < K) {
            long off = (long)k * HID + n0 + nn;
            v = isbf ? ((const uint16_t*)W)[off] : f2bf(((const float*)W)[off]);
        }
        s[kk][nn] = v;
    }
    __syncthreads();
#pragma unroll
    for (int i = 0; i < 16; i++) {
        int idx = t + i * 256;
        int nn = idx >> 6, kk = idx & 63;
        Wt[(long)(n0 + nn) * Kpad + k0 + kk] = s[kk][nn];
    }
}

struct T3 { const void* src[3]; uint16_t* dst[3]; };
__global__ void k_transp3(T3 a, const int* flags) {
    __shared__ uint16_t s[64][65];
    int isbf = flags[0];
    const void* W = a.src[blockIdx.z];
    uint16_t* Wt = a.dst[blockIdx.z];
    int k0 = blockIdx.x * 64, n0 = blockIdx.y * 64;
    int t = threadIdx.x;
#pragma unroll
    for (int i = 0; i < 16; i++) {
        int idx = t + i * 256;
        int kk = idx >> 6, nn = idx & 63;
        long off = (long)(k0 + kk) * HID + n0 + nn;
        s[kk][nn] = isbf ? ((const uint16_t*)W)[off] : f2bf(((const float*)W)[off]);
    }
    __syncthreads();
#pragma unroll
    for (int i = 0; i < 16; i++) {
        int idx = t + i * 256;
        int nn = idx >> 6, kk = idx & 63;
        Wt[(long)(n0 + nn) * HID + k0 + kk] = s[kk][nn];
    }
}

// Wf0 [6952][256] -> [256][7040], per-machine stride 320 (zero pad 316..319)
__global__ void k_transp_wf0(const void* W, uint16_t* Wt, const int* flags) {
    __shared__ uint16_t s[64][65];
    int isbf = flags[0];
    int g0 = blockIdx.x * 64, n0 = blockIdx.y * 64;
    int t = threadIdx.x;
#pragma unroll
    for (int i = 0; i < 16; i++) {
        int idx = t + i * 256;
        int gg = idx >> 6, nn = idx & 63;
        int gk = g0 + gg;
        int m = gk / PERM2;
        int k2 = gk - m * PERM2;
        uint16_t v = 0;
        if (k2 < PERM) {
            long off = (long)(m * PERM + k2) * HID + n0 + nn;
            v = isbf ? ((const uint16_t*)W)[off] : f2bf(((const float*)W)[off]);
        }
        s[gg][nn] = v;
    }
    __syncthreads();
#pragma unroll
    for (int i = 0; i < 16; i++) {
        int idx = t + i * 256;
        int nn = idx >> 6, gg = idx & 63;
        Wt[(long)(n0 + nn) * FLATP2 + g0 + gg] = s[gg][nn];
    }
}

// ---------------- CSR build ----------------
__global__ void k_count(const void* ei, int E, int* count, int* rank, const int* flags) {
    int e0 = (blockIdx.x * blockDim.x + threadIdx.x) * 2;
    if (e0 >= E) return;
    int i64 = flags[1];
    int c0, c1 = -1;
    if (i64) {
        const long long* p = (const long long*)ei + E + e0;
        c0 = (int)p[0];
        if (e0 + 1 < E) c1 = (int)p[1];
    } else {
        const int* p = (const int*)ei + E + e0;
        c0 = p[0];
        if (e0 + 1 < E) c1 = p[1];
    }
    rank[e0] = atomicAdd(&count[c0], 1);
    if (c1 >= 0) rank[e0 + 1] = atomicAdd(&count[c1], 1);
}

// hierarchical exclusive scan ; 44 blocks x 1024
__global__ void k_scan1(const int* count, int* rowptr, int* bsum, int n) {
    __shared__ int sd[1024];
    int i = blockIdx.x * 1024 + threadIdx.x;
    int v = (i < n) ? count[i] : 0;
    sd[threadIdx.x] = v;
    __syncthreads();
    for (int off = 1; off < 1024; off <<= 1) {
        int t = (threadIdx.x >= (unsigned)off) ? sd[threadIdx.x - off] : 0;
        __syncthreads();
        sd[threadIdx.x] += t;
        __syncthreads();
    }
    if (i < n) rowptr[i] = sd[threadIdx.x] - v;
    if (threadIdx.x == 1023) bsum[blockIdx.x] = sd[1023];
}

// scan of 44 block sums folded in: each block computes its own prefix
__global__ void k_scan3(int* rowptr, const int* bsum, int nb, int n) {
    __shared__ int sboff;
    if (threadIdx.x == 0) {
        int acc = 0;
        for (int i = 0; i < (int)blockIdx.x; i++) acc += bsum[i];
        sboff = acc;
        if ((int)blockIdx.x == nb - 1) rowptr[n] = acc + bsum[nb - 1];
    }
    __syncthreads();
    int i = blockIdx.x * 1024 + threadIdx.x;
    if (i < n) rowptr[i] += sboff;
}

// fill interleaved CSR uint2{src, raw_w_bits}; 2 edges per thread, no atomics
__global__ void k_fill(const void* ei, const void* ew, const int* rowptr, const int* rank,
                       uint2* adj, int E, const int* flags) {
    int e0 = (blockIdx.x * blockDim.x + threadIdx.x) * 2;
    if (e0 >= E) return;
    int i64 = flags[1], isbf = flags[0];
    int r0, r1 = -1, c0, c1 = -1;
    if (i64) {
        const long long* pr = (const long long*)ei + e0;
        const long long* pc = (const long long*)ei + E + e0;
        r0 = (int)pr[0]; c0 = (int)pc[0];
        if (e0 + 1 < E) { r1 = (int)pr[1]; c1 = (int)pc[1]; }
    } else {
        const int* pr = (const int*)ei + e0;
        const int* pc = (const int*)ei + E + e0;
        r0 = pr[0]; c0 = pc[0];
        if (e0 + 1 < E) { r1 = pr[1]; c1 = pc[1]; }
    }
    float w0, w1 = 0.f;
    if (isbf) {
        uint32_t ww = ((const uint32_t*)ew)[e0 >> 1];
        w0 = bf2f((uint16_t)(ww & 0xffff));
        w1 = bf2f((uint16_t)(ww >> 16));
    } else {
        float2 f = ((const float2*)ew)[e0 >> 1];
        w0 = f.x; w1 = f.y;
    }
    int2 rk = *(const int2*)(rank + e0);
    uint2 v0; v0.x = (uint32_t)r0; v0.y = __float_as_uint(w0);
    adj[rowptr[c0] + rk.x] = v0;
    if (c1 >= 0) {
        uint2 v1; v1.x = (uint32_t)r1; v1.y = __float_as_uint(w1);
        adj[rowptr[c1] + rk.y] = v1;
    }
}

// dinv = 1/sqrt(1 + row-sum of raw ew)
__global__ void k_rowsum(const int* rowptr, const uint2* adj, float* dinv, int n) {
    int i = blockIdx.x * blockDim.x + threadIdx.x;
    if (i >= n) return;
    int s = rowptr[i], e = rowptr[i + 1];
    double d = 1.0;
    for (int p = s; p < e; p++) d += (double)__uint_as_float(adj[p].y);
    dinv[i] = (float)(1.0 / sqrt(d));
}

// ---------------- layer-1 pre-aggregation on x64 [N][64], unroll x4 ----------------
__global__ __launch_bounds__(256) void k_aggx(const uint16_t* __restrict__ x64,
                                              const float* __restrict__ dinv,
                                              const int* __restrict__ rowptr,
                                              const uint2* __restrict__ adj,
                                              uint16_t* __restrict__ xa, int n) {
    __shared__ uint2 sadj[8][32];
    int hv = threadIdx.x >> 5;
    int l = threadIdx.x & 31;
    int node = blockIdx.x * 8 + hv;
    if (node >= n) return;
    const uint32_t* xu = (const uint32_t*)x64;
    float di = dinv[node];
    float c2 = di * di;
    uint32_t h = xu[(long)node * 32 + l];
    float a0 = c2 * bf2f((uint16_t)(h & 0xffff));
    float a1 = c2 * bf2f((uint16_t)(h >> 16));
    int s = rowptr[node], e = rowptr[node + 1];
    for (int base = s; base < e; base += 32) {
        int m = e - base; if (m > 32) m = 32;
        if (l < m) {
            uint2 a = adj[base + l];
            float w = __uint_as_float(a.y) * dinv[a.x] * di;
            uint2 p; p.x = a.x; p.y = __float_as_uint(w);
            sadj[hv][l] = p;
        }
        int t = 0;
        for (; t + 4 <= m; t += 4) {
            uint2 e0 = sadj[hv][t], e1 = sadj[hv][t + 1], e2 = sadj[hv][t + 2], e3 = sadj[hv][t + 3];
            uint32_t v0 = xu[(long)e0.x * 32 + l];
            uint32_t v1 = xu[(long)e1.x * 32 + l];
            uint32_t v2 = xu[(long)e2.x * 32 + l];
            uint32_t v3 = xu[(long)e3.x * 32 + l];
            float w0 = __uint_as_float(e0.y), w1 = __uint_as_float(e1.y);
            float w2 = __uint_as_float(e2.y), w3 = __uint_as_float(e3.y);
            a0 += w0 * bf2f((uint16_t)(v0 & 0xffff)); a1 += w0 * bf2f((uint16_t)(v0 >> 16));
            a0 += w1 * bf2f((uint16_t)(v1 & 0xffff)); a1 += w1 * bf2f((uint16_t)(v1 >> 16));
            a0 += w2 * bf2f((uint16_t)(v2 & 0xffff)); a1 += w2 * bf2f((uint16_t)(v2 >> 16));
            a0 += w3 * bf2f((uint16_t)(v3 & 0xffff)); a1 += w3 * bf2f((uint16_t)(v3 >> 16));
        }
        for (; t < m; t++) {
            uint2 e0 = sadj[hv][t];
            uint32_t v0 = xu[(long)e0.x * 32 + l];
            float w0 = __uint_as_float(e0.y);
            a0 += w0 * bf2f((uint16_t)(v0 & 0xffff));
            a1 += w0 * bf2f((uint16_t)(v0 >> 16));
        }
    }
    ((uint32_t*)xa)[(long)node * 32 + l] =
        (uint32_t)f2bf(a0) | ((uint32_t)f2bf(a1) << 16);
}

// ---------------- 256-col aggregation: half-wave/node, uint4 rows, unroll x4 ----
__device__ __forceinline__ void fma8(float* acc, float w, uint4 v) {
    acc[0] += w * bf2f((uint16_t)(v.x & 0xffff));
    acc[1] += w * bf2f((uint16_t)(v.x >> 16));
    acc[2] += w * bf2f((uint16_t)(v.y & 0xffff));
    acc[3] += w * bf2f((uint16_t)(v.y >> 16));
    acc[4] += w * bf2f((uint16_t)(v.z & 0xffff));
    acc[5] += w * bf2f((uint16_t)(v.z >> 16));
    acc[6] += w * bf2f((uint16_t)(v.w & 0xffff));
    acc[7] += w * bf2f((uint16_t)(v.w >> 16));
}

__global__ __launch_bounds__(256) void k_aggb(const uint16_t* __restrict__ hw,
                                              const float* __restrict__ dinv,
                                              const int* __restrict__ rowptr,
                                              const uint2* __restrict__ adj,
                                              const float* __restrict__ bias,
                                              uint16_t* __restrict__ out, int n) {
    __shared__ uint2 sadj[8][32];
    int hv = threadIdx.x >> 5;
    int l = threadIdx.x & 31;
    int node = blockIdx.x * 8 + hv;
    if (node >= n) return;
    const uint4* hw4 = (const uint4*)hw;
    float di = dinv[node];
    float c2 = di * di;
    uint4 h = hw4[(long)node * 32 + l];
    float acc[8];
    acc[0] = c2 * bf2f((uint16_t)(h.x & 0xffff));
    acc[1] = c2 * bf2f((uint16_t)(h.x >> 16));
    acc[2] = c2 * bf2f((uint16_t)(h.y & 0xffff));
    acc[3] = c2 * bf2f((uint16_t)(h.y >> 16));
    acc[4] = c2 * bf2f((uint16_t)(h.z & 0xffff));
    acc[5] = c2 * bf2f((uint16_t)(h.z >> 16));
    acc[6] = c2 * bf2f((uint16_t)(h.w & 0xffff));
    acc[7] = c2 * bf2f((uint16_t)(h.w >> 16));
    int s = rowptr[node], e = rowptr[node + 1];
    for (int base = s; base < e; base += 32) {
        int m = e - base; if (m > 32) m = 32;
        if (l < m) {
            uint2 a = adj[base + l];
            float w = __uint_as_float(a.y) * dinv[a.x] * di;
            uint2 p; p.x = a.x; p.y = __float_as_uint(w);
            sadj[hv][l] = p;
        }
        int t = 0;
        for (; t + 4 <= m; t += 4) {
            uint2 e0 = sadj[hv][t], e1 = sadj[hv][t + 1], e2 = sadj[hv][t + 2], e3 = sadj[hv][t + 3];
            uint4 v0 = hw4[(long)e0.x * 32 + l];
            uint4 v1 = hw4[(long)e1.x * 32 + l];
            uint4 v2 = hw4[(long)e2.x * 32 + l];
            uint4 v3 = hw4[(long)e3.x * 32 + l];
            fma8(acc, __uint_as_float(e0.y), v0);
            fma8(acc, __uint_as_float(e1.y), v1);
            fma8(acc, __uint_as_float(e2.y), v2);
            fma8(acc, __uint_as_float(e3.y), v3);
        }
        for (; t < m; t++) {
            uint2 e0 = sadj[hv][t];
            uint4 v0 = hw4[(long)e0.x * 32 + l];
            fma8(acc, __uint_as_float(e0.y), v0);
        }
    }
    float4 ba = ((const float4*)bias)[l * 2];
    float4 bb = ((const float4*)bias)[l * 2 + 1];
    acc[0] += ba.x; acc[1] += ba.y; acc[2] += ba.z; acc[3] += ba.w;
    acc[4] += bb.x; acc[5] += bb.y; acc[6] += bb.z; acc[7] += bb.w;
#pragma unroll
    for (int k = 0; k < 8; k++) acc[k] = acc[k] > 0.f ? acc[k] : NEG * acc[k];
    uint4 o;
    o.x = (uint32_t)f2bf(acc[0]) | ((uint32_t)f2bf(acc[1]) << 16);
    o.y = (uint32_t)f2bf(acc[2]) | ((uint32_t)f2bf(acc[3]) << 16);
    o.z = (uint32_t)f2bf(acc[4]) | ((uint32_t)f2bf(acc[5]) << 16);
    o.w = (uint32_t)f2bf(acc[6]) | ((uint32_t)f2bf(acc[7]) << 16);
    ((uint4*)out)[(long)node * 32 + l] = o;
}

// ---------------- bf16 MFMA GEMM (plain A) ----------------
__global__ __launch_bounds__(256) void k_mgemm(const uint16_t* __restrict__ A,
                                               const uint16_t* __restrict__ Bt,
                                               float* __restrict__ part,
                                               uint16_t* __restrict__ outb,
                                               const float* __restrict__ bias,
                                               int M, int K, int Kc, int act) {
    __shared__ uint16_t As[128 * 40];
    __shared__ uint16_t Bs[128 * 40];
    int tid = threadIdx.x;
    int lane = tid & 63, wv = tid >> 6;
    int quad = lane >> 4, l15 = lane & 15;
    int row0 = blockIdx.y * 128, col0 = blockIdx.x * 128;
    int kbeg = blockIdx.z * Kc;
    int kend = kbeg + Kc; if (kend > K) kend = K;
    int arow = (wv >> 1) * 64;
    int bcol = (wv & 1) * 64;

    f32x4 acc[4][4];
#pragma unroll
    for (int i = 0; i < 4; i++)
#pragma unroll
        for (int j = 0; j < 4; j++) acc[i][j] = (f32x4){0.f, 0.f, 0.f, 0.f};

    for (int kc = kbeg; kc < kend; kc += 32) {
#pragma unroll
        for (int i = 0; i < 2; i++) {
            int idx = tid + i * 256;
            int r = idx >> 2, cq = idx & 3;
            uint4 va = *(const uint4*)(A + (long)(row0 + r) * K + kc + cq * 8);
            *(uint4*)(&As[r * 40 + cq * 8]) = va;
            uint4 vb = *(const uint4*)(Bt + (long)(col0 + r) * K + kc + cq * 8);
            *(uint4*)(&Bs[r * 40 + cq * 8]) = vb;
        }
        __syncthreads();
        bf16x8 af[4], bfr[4];
#pragma unroll
        for (int i = 0; i < 4; i++)
            af[i] = __builtin_bit_cast(bf16x8,
                *(const uint4*)(&As[(arow + i * 16 + l15) * 40 + quad * 8]));
#pragma unroll
        for (int j = 0; j < 4; j++)
            bfr[j] = __builtin_bit_cast(bf16x8,
                *(const uint4*)(&Bs[(bcol + j * 16 + l15) * 40 + quad * 8]));
#pragma unroll
        for (int i = 0; i < 4; i++)
#pragma unroll
            for (int j = 0; j < 4; j++)
                acc[i][j] = __builtin_amdgcn_mfma_f32_16x16x32_bf16(af[i], bfr[j], acc[i][j], 0, 0, 0);
        __syncthreads();
    }

#pragma unroll
    for (int i = 0; i < 4; i++)
#pragma unroll
        for (int j = 0; j < 4; j++) {
            int row = row0 + arow + i * 16 + quad * 4;
            int col = col0 + bcol + j * 16 + l15;
#pragma unroll
            for (int reg = 0; reg < 4; reg++) {
                float v = acc[i][j][reg];
                long o = (long)(row + reg) * HID + col;
                if (part) part[(long)blockIdx.z * M * HID + o] = v;
                else {
                    if (bias) v += bias[col];
                    if (act) v = v > 0.f ? v : NEG * v;
                    outb[o] = f2bf(v);
                }
            }
        }
}

// ---------------- bf16 MFMA GEMM, VIRTUAL flat A (mlp0) ----------------
__global__ __launch_bounds__(256) void k_mgemm_flat(const uint16_t* __restrict__ h2,
                                                    const uint16_t* __restrict__ x64,
                                                    const uint16_t* __restrict__ Bt,
                                                    float* __restrict__ part,
                                                    int M, int Kc) {
    __shared__ uint16_t As[128 * 40];
    __shared__ uint16_t Bs[128 * 40];
    int tid = threadIdx.x;
    int lane = tid & 63, wv = tid >> 6;
    int quad = lane >> 4, l15 = lane & 15;
    int row0 = blockIdx.y * 128, col0 = blockIdx.x * 128;
    int kbeg = blockIdx.z * Kc;
    int kend = kbeg + Kc; if (kend > FLATP2) kend = FLATP2;
    int arow = (wv >> 1) * 64;
    int bcol = (wv & 1) * 64;

    f32x4 acc[4][4];
#pragma unroll
    for (int i = 0; i < 4; i++)
#pragma unroll
        for (int j = 0; j < 4; j++) acc[i][j] = (f32x4){0.f, 0.f, 0.f, 0.f};

    for (int kc = kbeg; kc < kend; kc += 32) {
#pragma unroll
        for (int i = 0; i < 2; i++) {
            int idx = tid + i * 256;
            int r = idx >> 2, cq = idx & 3;
            int gk = kc + cq * 8;
            int m = gk / PERM2;
            int k2 = gk - m * PERM2;
            long node = (long)(row0 + r) * MACH + m;
            uint4 va = (k2 < HID)
                ? *(const uint4*)(h2 + node * HID + k2)
                : *(const uint4*)(x64 + node * 64 + (k2 - HID));
            *(uint4*)(&As[r * 40 + cq * 8]) = va;
            uint4 vb = *(const uint4*)(Bt + (long)(col0 + r) * FLATP2 + gk);
            *(uint4*)(&Bs[r * 40 + cq * 8]) = vb;
        }
        __syncthreads();
        bf16x8 af[4], bfr[4];
#pragma unroll
        for (int i = 0; i < 4; i++)
            af[i] = __builtin_bit_cast(bf16x8,
                *(const uint4*)(&As[(arow + i * 16 + l15) * 40 + quad * 8]));
#pragma unroll
        for (int j = 0; j < 4; j++)
            bfr[j] = __builtin_bit_cast(bf16x8,
                *(const uint4*)(&Bs[(bcol + j * 16 + l15) * 40 + quad * 8]));
#pragma unroll
        for (int i = 0; i < 4; i++)
#pragma unroll
            for (int j = 0; j < 4; j++)
                acc[i][j] = __builtin_amdgcn_mfma_f32_16x16x32_bf16(af[i], bfr[j], acc[i][j], 0, 0, 0);
        __syncthreads();
    }

#pragma unroll
    for (int i = 0; i < 4; i++)
#pragma unroll
        for (int j = 0; j < 4; j++) {
            int row = row0 + arow + i * 16 + quad * 4;
            int col = col0 + bcol + j * 16 + l15;
#pragma unroll
            for (int reg = 0; reg < 4; reg++)
                part[(long)blockIdx.z * M * HID + (long)(row + reg) * HID + col] = acc[i][j][reg];
        }
}

// ---------------- reduce split-K partials + bias + lrelu -> bf16 ----------------
__global__ void k_reduce(const float* __restrict__ part, const float* __restrict__ bias,
                         uint16_t* __restrict__ out, int MN, int S) {
    int i = blockIdx.x * blockDim.x + threadIdx.x;
    if (i >= MN) return;
    float v = 0.f;
    for (int s = 0; s < S; s++) v += part[(long)s * MN + i];
    v += bias[i & (HID - 1)];
    v = v > 0.f ? v : NEG * v;
    out[i] = f2bf(v);
}

// ---------------- fused MLP tail: z0 -> mlp1 -> mlp2 -> out ----------------
__global__ __launch_bounds__(256) void k_tail(const uint16_t* __restrict__ z0,
                                              const uint16_t* __restrict__ Wf1t,
                                              const float* __restrict__ bf1,
                                              const uint16_t* __restrict__ Wf2t,
                                              const float* __restrict__ bf2,
                                              const float* __restrict__ Wo,
                                              const float* __restrict__ bo,
                                              void* out, const int* flags) {
    __shared__ uint16_t z1s[16 * 256];
    __shared__ uint16_t z2s[16 * 256];
    int tid = threadIdx.x;
    int lane = tid & 63, wv = tid >> 6;
    int quad = lane >> 4, l15 = lane & 15;
    int rows0 = blockIdx.x * 16;
    int nw = wv * 64;

    {
        f32x4 acc[4];
#pragma unroll
        for (int j = 0; j < 4; j++) acc[j] = (f32x4){0.f, 0.f, 0.f, 0.f};
        for (int kc = 0; kc < HID; kc += 32) {
            bf16x8 a = __builtin_bit_cast(bf16x8,
                *(const uint4*)(z0 + (long)(rows0 + l15) * HID + kc + quad * 8));
#pragma unroll
            for (int j = 0; j < 4; j++) {
                bf16x8 b = __builtin_bit_cast(bf16x8,
                    *(const uint4*)(Wf1t + (long)(nw + j * 16 + l15) * HID + kc + quad * 8));
                acc[j] = __builtin_amdgcn_mfma_f32_16x16x32_bf16(a, b, acc[j], 0, 0, 0);
            }
        }
#pragma unroll
        for (int j = 0; j < 4; j++) {
            int col = nw + j * 16 + l15;
            float bj = bf1[col];
#pragma unroll
            for (int reg = 0; reg < 4; reg++) {
                float v = acc[j][reg] + bj;
                v = v > 0.f ? v : NEG * v;
                z1s[(quad * 4 + reg) * 256 + col] = f2bf(v);
            }
        }
    }
    __syncthreads();

    {
        f32x4 acc[4];
#pragma unroll
        for (int j = 0; j < 4; j++) acc[j] = (f32x4){0.f, 0.f, 0.f, 0.f};
        for (int kc = 0; kc < HID; kc += 32) {
            bf16x8 a = __builtin_bit_cast(bf16x8,
                *(const uint4*)(&z1s[l15 * 256 + kc + quad * 8]));
#pragma unroll
            for (int j = 0; j < 4; j++) {
                bf16x8 b = __builtin_bit_cast(bf16x8,
                    *(const uint4*)(Wf2t + (long)(nw + j * 16 + l15) * HID + kc + quad * 8));
                acc[j] = __builtin_amdgcn_mfma_f32_16x16x32_bf16(a, b, acc[j], 0, 0, 0);
            }
        }
#pragma unroll
        for (int j = 0; j < 4; j++) {
            int col = nw + j * 16 + l15;
            float bj = bf2[col];
#pragma unroll
            for (int reg = 0; reg < 4; reg++) {
                float v = acc[j][reg] + bj;
                v = v > 0.f ? v : NEG * v;
                z2s[(quad * 4 + reg) * 256 + col] = f2bf(v);
            }
        }
    }
    __syncthreads();

    if (tid < 64) {
        int r = tid >> 2, o = tid & 3;
        float acc = bo[o];
        for (int k = 0; k < HID; k++)
            acc += bf2f(z2s[r * 256 + k]) * Wo[k * 4 + o];
        long idx = (long)(rows0 + r) * 4 + o;
        if (flags[0]) ((uint16_t*)out)[idx] = f2bf(acc);
        else          ((float*)out)[idx] = acc;
    }
}

// ---------------- host ----------------
extern "C" void kernel_launch(void* const* d_in, const int* in_sizes, int n_in,
                              void* d_out, int out_size, void* d_ws, size_t ws_size,
                              hipStream_t stream) {
    const int N  = in_sizes[0] / FEA;   // 45056
    const int E  = in_sizes[2];         // 720896
    const int Bn = N / MACH;            // 2048
    const int S0 = 8, Kc0 = 896;        // ceil(7040/896)=8 slices, grid z=8 -> 256 blocks

    char* ws = (char*)d_ws;
    size_t off = 0;
    auto alloc = [&](size_t bytes) -> char* {
        char* p = ws + off;
        off = (off + bytes + 255) & ~(size_t)255;
        return p;
    };

    int*      flags  = (int*)     alloc(64);
    uint16_t* x64    = (uint16_t*)alloc((size_t)N * 64 * 2);
    uint16_t* xa     = (uint16_t*)alloc((size_t)N * 64 * 2);
    uint16_t* W1t    = (uint16_t*)alloc((size_t)HID * 64 * 2);
    uint16_t* W2t    = (uint16_t*)alloc((size_t)HID * HID * 2);
    uint16_t* Wf0t   = (uint16_t*)alloc((size_t)HID * FLATP2 * 2);
    uint16_t* Wf1t   = (uint16_t*)alloc((size_t)HID * HID * 2);
    uint16_t* Wf2t   = (uint16_t*)alloc((size_t)HID * HID * 2);
    float*    b1     = (float*)   alloc(HID * 4);
    float*    b2     = (float*)   alloc(HID * 4);
    float*    bf0    = (float*)   alloc(HID * 4);
    float*    bf1    = (float*)   alloc(HID * 4);
    float*    bf2    = (float*)   alloc(HID * 4);
    float*    Wo     = (float*)   alloc((size_t)HID * 4 * 4);
    float*    bo     = (float*)   alloc(4 * 4);
    int*      count  = (int*)     alloc((size_t)N * 4);
    int*      rank   = (int*)     alloc((size_t)E * 4);
    int*      rowptr = (int*)     alloc((size_t)(N + 1) * 4);
    int*      bsum   = (int*)     alloc(64 * 4);
    uint2*    adj    = (uint2*)   alloc((size_t)E * 8);
    float*    dinv   = (float*)   alloc((size_t)N * 4);
    uint16_t* P      = (uint16_t*)alloc((size_t)N * HID * 2);  // h1 / h2
    uint16_t* Q      = (uint16_t*)alloc((size_t)N * HID * 2);  // hw
    float*    part   = (float*)   alloc((size_t)S0 * Bn * HID * 4);
    uint16_t* z0     = (uint16_t*)alloc((size_t)Bn * HID * 2);
    (void)ws_size; (void)n_in; (void)out_size;

    // 1. detect + zero count
    k_detect_init<<<(N + 255) / 256, 256, 0, stream>>>(
        (const uint32_t*)d_in[2], (const uint32_t*)d_in[1], flags, count, N);

    // 2. conversions / transposes
    Cvt8 c8{};
    const void* s8[7] = { d_in[4], d_in[6], d_in[8], d_in[10], d_in[12], d_in[13], d_in[14] };
    float* d8[7] = { b1, b2, bf0, bf1, bf2, Wo, bo };
    long n8[7] = { HID, HID, HID, HID, HID, (long)HID * 4, 4 };
    c8.cnt = 7;
    c8.prefix[0] = 0;
    for (int t = 0; t < 7; t++) { c8.src[t] = s8[t]; c8.dst[t] = d8[t]; c8.prefix[t + 1] = c8.prefix[t] + n8[t]; }
    c8.prefix[8] = c8.prefix[7];
    k_cvt_all<<<2048, 256, 0, stream>>>(d_in[0], x64, N, c8, flags);
    k_transp<<<dim3(1, 4), 256, 0, stream>>>(d_in[3], W1t, FEA, 64, flags);
    T3 t3{};
    t3.src[0] = d_in[5];  t3.dst[0] = W2t;
    t3.src[1] = d_in[9];  t3.dst[1] = Wf1t;
    t3.src[2] = d_in[11]; t3.dst[2] = Wf2t;
    k_transp3<<<dim3(4, 4, 3), 256, 0, stream>>>(t3, flags);
    k_transp_wf0<<<dim3(FLATP2 / 64, 4), 256, 0, stream>>>(d_in[7], Wf0t, flags);

    // 3. CSR (one atomic pass) + degree from CSR
    k_count<<<(E / 2 + 255) / 256, 256, 0, stream>>>(d_in[1], E, count, rank, flags);
    int nb = (N + 1023) / 1024;          // 44
    k_scan1<<<nb, 1024, 0, stream>>>(count, rowptr, bsum, N);
    k_scan3<<<nb, 1024, 0, stream>>>(rowptr, bsum, nb, N);
    k_fill<<<(E / 2 + 255) / 256, 256, 0, stream>>>(d_in[1], d_in[2], rowptr, rank, adj, E, flags);
    k_rowsum<<<(N + 255) / 256, 256, 0, stream>>>(rowptr, adj, dinv, N);

    // 4. GCN layer 1: xa = agg(x64) ; h1 = lrelu(xa @ W1t + b1)
    k_aggx<<<(N + 7) / 8, 256, 0, stream>>>(x64, dinv, rowptr, adj, xa, N);
    k_mgemm<<<dim3(2, N / 128, 1), 256, 0, stream>>>(xa, W1t, nullptr, P, b1, N, 64, 64, 1);

    // 5. GCN layer 2: hw = h1 @ W2t ; h2 = agg(hw) + b2, lrelu
    k_mgemm<<<dim3(2, N / 128, 1), 256, 0, stream>>>(P, W2t, nullptr, Q, nullptr, N, HID, HID, 0);
    k_aggb<<<(N + 7) / 8, 256, 0, stream>>>(Q, dinv, rowptr, adj, b2, P, N);

    // 6. mlp0: virtual-flat split-K (S=8, Kc=896)
    k_mgemm_flat<<<dim3(2, Bn / 128, S0), 256, 0, stream>>>(P, x64, Wf0t, part, Bn, Kc0);
    k_reduce<<<(Bn * HID + 255) / 256, 256, 0, stream>>>(part, bf0, z0, Bn * HID, S0);

    // 7. fused tail: mlp1 -> mlp2 -> out
    k_tail<<<Bn / 16, 256, 0, stream>>>(z0, Wf1t, bf1, Wf2t, bf2, Wo, bo, d_out, flags);
}

// Round 6
// 321.666 us; speedup vs baseline: 4.9692x; 1.0698x over previous
//
#include <hip/hip_runtime.h>
#include <stdint.h>

#define FEA 60
#define HID 256
#define MACH 22
#define PERM 316             // HID + FEA (reference layout)
#define PERM2 320            // padded per-machine stride (mult of 8)
#define FLATP2 (MACH * PERM2)   // 7040
#define NEG 0.01f
#define BCAP 64              // adjacency bucket capacity (max deg of Poisson(16) ~35)

typedef __bf16 bf16x8 __attribute__((ext_vector_type(8)));
typedef float f32x4 __attribute__((ext_vector_type(4)));

__device__ __forceinline__ float bf2f(uint16_t u) {
    return __uint_as_float(((uint32_t)u) << 16);
}
__device__ __forceinline__ uint16_t f2bf(float f) {   // RNE
    uint32_t x = __float_as_uint(f);
    return (uint16_t)((x + 0x7fffu + ((x >> 16) & 1u)) >> 16);
}

// ---------------- detect dtypes + zero count ----------------
// flags[0]=1 if float tensors bf16 ; flags[1]=1 if edge_index int64
__global__ void k_detect_init(const uint32_t* ew_w, const uint32_t* ei_w, int* flags,
                              int* count, int n) {
    int i = blockIdx.x * blockDim.x + threadIdx.x;
    if (i < n) count[i] = 0;
    if (blockIdx.x == 0) {
        __shared__ int c15, onz;
        if (threadIdx.x == 0) { c15 = 0; onz = 0; }
        __syncthreads();
        int a = 0, b = 0;
        for (int k = threadIdx.x; k < 1024; k += 256) {
            if (ew_w[k] & 0x8000u) a++;
            if (ei_w[2 * k + 1] != 0u) b++;
        }
        atomicAdd(&c15, a); atomicAdd(&onz, b);
        __syncthreads();
        if (threadIdx.x == 0) {
            flags[0] = (c15 <= 100) ? 1 : 0;
            flags[1] = (onz < 8) ? 1 : 0;
        }
    }
}

// ---------------- conversions: x64 + small fp32 tensors, one kernel ----------------
struct Cvt8 {
    const void* src[8];
    float* dst[8];
    long prefix[9];
    int cnt;
};

__global__ void k_cvt_all(const void* xsrc, uint16_t* x64, int n, Cvt8 a, const int* flags) {
    int isbf = flags[0];
    long nx = (long)n * 64;
    long total = nx + a.prefix[a.cnt];
    for (long i = (long)blockIdx.x * blockDim.x + threadIdx.x; i < total;
         i += (long)gridDim.x * blockDim.x) {
        if (i < nx) {
            int col = (int)(i & 63);
            long row = i >> 6;
            uint16_t v = 0;
            if (col < FEA) {
                long s = row * FEA + col;
                v = isbf ? ((const uint16_t*)xsrc)[s] : f2bf(((const float*)xsrc)[s]);
            }
            x64[i] = v;
        } else {
            long ii = i - nx;
            int t = 0;
            while (ii >= a.prefix[t + 1]) t++;
            long j = ii - a.prefix[t];
            a.dst[t][j] = isbf ? bf2f(((const uint16_t*)a.src[t])[j])
                               : ((const float*)a.src[t])[j];
        }
    }
}

// ---------------- merged weight transposes (one launch) ----------------
// blocks [0,440): Wf0 [6952][256] -> [256][7040] (per-machine stride 320, zero pad)
// blocks [440,488): three 256x256 transposes -> [256][256]
// blocks [488,492): W1 [60][256] -> [256][64] zero-padded
struct PrepW {
    const void* wf0; uint16_t* wf0t;
    const void* src3[3]; uint16_t* dst3[3];
    const void* w1; uint16_t* w1t;
};

__global__ __launch_bounds__(256) void k_prep(PrepW a, const int* flags) {
    __shared__ uint16_t s[64][65];
    int isbf = flags[0];
    int b = blockIdx.x;
    int t = threadIdx.x;
    if (b < 440) {
        int g0 = (b >> 2) * 64, n0 = (b & 3) * 64;
#pragma unroll
        for (int i = 0; i < 16; i++) {
            int idx = t + i * 256;
            int gg = idx >> 6, nn = idx & 63;
            int gk = g0 + gg;
            int m = gk / PERM2;
            int k2 = gk - m * PERM2;
            uint16_t v = 0;
            if (k2 < PERM) {
                long off = (long)(m * PERM + k2) * HID + n0 + nn;
                v = isbf ? ((const uint16_t*)a.wf0)[off] : f2bf(((const float*)a.wf0)[off]);
            }
            s[gg][nn] = v;
        }
        __syncthreads();
#pragma unroll
        for (int i = 0; i < 16; i++) {
            int idx = t + i * 256;
            int nn = idx >> 6, gg = idx & 63;
            a.wf0t[(long)(n0 + nn) * FLATP2 + g0 + gg] = s[gg][nn];
        }
    } else if (b < 488) {
        int idx0 = b - 440;
        int z = idx0 >> 4, r = idx0 & 15;
        int k0 = (r >> 2) * 64, n0 = (r & 3) * 64;
        const void* W = a.src3[z];
        uint16_t* Wt = a.dst3[z];
#pragma unroll
        for (int i = 0; i < 16; i++) {
            int idx = t + i * 256;
            int kk = idx >> 6, nn = idx & 63;
            long off = (long)(k0 + kk) * HID + n0 + nn;
            s[kk][nn] = isbf ? ((const uint16_t*)W)[off] : f2bf(((const float*)W)[off]);
        }
        __syncthreads();
#pragma unroll
        for (int i = 0; i < 16; i++) {
            int idx = t + i * 256;
            int nn = idx >> 6, kk = idx & 63;
            Wt[(long)(n0 + nn) * HID + k0 + kk] = s[kk][nn];
        }
    } else {
        int n0 = (b - 488) * 64;
#pragma unroll
        for (int i = 0; i < 16; i++) {
            int idx = t + i * 256;
            int kk = idx >> 6, nn = idx & 63;
            uint16_t v = 0;
            if (kk < FEA) {
                long off = (long)kk * HID + n0 + nn;
                v = isbf ? ((const uint16_t*)a.w1)[off] : f2bf(((const float*)a.w1)[off]);
            }
            s[kk][nn] = v;
        }
        __syncthreads();
#pragma unroll
        for (int i = 0; i < 16; i++) {
            int idx = t + i * 256;
            int nn = idx >> 6, kk = idx & 63;
            a.w1t[(long)(n0 + nn) * 64 + kk] = s[kk][nn];
        }
    }
}

// ---------------- bucket-CSR scatter: ONE pass, one atomic/edge ----------------
__global__ void k_scatter(const void* ei, const void* ew, int* count, uint2* adj,
                          int E, const int* flags) {
    int e0 = (blockIdx.x * blockDim.x + threadIdx.x) * 2;
    if (e0 >= E) return;
    int i64 = flags[1], isbf = flags[0];
    int r0, r1 = -1, c0, c1 = -1;
    if (i64) {
        const long long* pr = (const long long*)ei + e0;
        const long long* pc = (const long long*)ei + E + e0;
        r0 = (int)pr[0]; c0 = (int)pc[0];
        if (e0 + 1 < E) { r1 = (int)pr[1]; c1 = (int)pc[1]; }
    } else {
        const int* pr = (const int*)ei + e0;
        const int* pc = (const int*)ei + E + e0;
        r0 = pr[0]; c0 = pc[0];
        if (e0 + 1 < E) { r1 = pr[1]; c1 = pc[1]; }
    }
    float w0, w1 = 0.f;
    if (isbf) {
        uint32_t ww = ((const uint32_t*)ew)[e0 >> 1];
        w0 = bf2f((uint16_t)(ww & 0xffff));
        w1 = bf2f((uint16_t)(ww >> 16));
    } else {
        float2 f = ((const float2*)ew)[e0 >> 1];
        w0 = f.x; w1 = f.y;
    }
    int p0 = atomicAdd(&count[c0], 1);
    uint2 v0; v0.x = (uint32_t)r0; v0.y = __float_as_uint(w0);
    adj[((long)c0 << 6) + p0] = v0;
    if (c1 >= 0) {
        int p1 = atomicAdd(&count[c1], 1);
        uint2 v1; v1.x = (uint32_t)r1; v1.y = __float_as_uint(w1);
        adj[((long)c1 << 6) + p1] = v1;
    }
}

// dinv = 1/sqrt(1 + row-sum of raw ew) over bucket
__global__ void k_rowsum(const int* count, const uint2* adj, float* dinv, int n) {
    int i = blockIdx.x * blockDim.x + threadIdx.x;
    if (i >= n) return;
    int cnt = count[i];
    const uint2* row = adj + ((long)i << 6);
    double d = 1.0;
    for (int p = 0; p < cnt; p++) d += (double)__uint_as_float(row[p].y);
    dinv[i] = (float)(1.0 / sqrt(d));
}

// ---------------- layer-1 pre-aggregation on x64 [N][64] ----------------
__global__ __launch_bounds__(256) void k_aggx(const uint16_t* __restrict__ x64,
                                              const float* __restrict__ dinv,
                                              const int* __restrict__ count,
                                              const uint2* __restrict__ adj,
                                              uint16_t* __restrict__ xa, int n) {
    __shared__ uint2 sadj[8][32];
    int hv = threadIdx.x >> 5;
    int l = threadIdx.x & 31;
    int node = blockIdx.x * 8 + hv;
    if (node >= n) return;
    const uint32_t* xu = (const uint32_t*)x64;
    float di = dinv[node];
    float c2 = di * di;
    uint32_t h = xu[(long)node * 32 + l];
    float a0 = c2 * bf2f((uint16_t)(h & 0xffff));
    float a1 = c2 * bf2f((uint16_t)(h >> 16));
    int cnt = count[node];
    const uint2* row = adj + ((long)node << 6);
    for (int base = 0; base < cnt; base += 32) {
        int m = cnt - base; if (m > 32) m = 32;
        if (l < m) {
            uint2 a = row[base + l];
            float w = __uint_as_float(a.y) * dinv[a.x] * di;
            uint2 p; p.x = a.x; p.y = __float_as_uint(w);
            sadj[hv][l] = p;
        }
        int t = 0;
        for (; t + 4 <= m; t += 4) {
            uint2 e0 = sadj[hv][t], e1 = sadj[hv][t + 1], e2 = sadj[hv][t + 2], e3 = sadj[hv][t + 3];
            uint32_t v0 = xu[(long)e0.x * 32 + l];
            uint32_t v1 = xu[(long)e1.x * 32 + l];
            uint32_t v2 = xu[(long)e2.x * 32 + l];
            uint32_t v3 = xu[(long)e3.x * 32 + l];
            float w0 = __uint_as_float(e0.y), w1 = __uint_as_float(e1.y);
            float w2 = __uint_as_float(e2.y), w3 = __uint_as_float(e3.y);
            a0 += w0 * bf2f((uint16_t)(v0 & 0xffff)); a1 += w0 * bf2f((uint16_t)(v0 >> 16));
            a0 += w1 * bf2f((uint16_t)(v1 & 0xffff)); a1 += w1 * bf2f((uint16_t)(v1 >> 16));
            a0 += w2 * bf2f((uint16_t)(v2 & 0xffff)); a1 += w2 * bf2f((uint16_t)(v2 >> 16));
            a0 += w3 * bf2f((uint16_t)(v3 & 0xffff)); a1 += w3 * bf2f((uint16_t)(v3 >> 16));
        }
        for (; t < m; t++) {
            uint2 e0 = sadj[hv][t];
            uint32_t v0 = xu[(long)e0.x * 32 + l];
            float w0 = __uint_as_float(e0.y);
            a0 += w0 * bf2f((uint16_t)(v0 & 0xffff));
            a1 += w0 * bf2f((uint16_t)(v0 >> 16));
        }
    }
    ((uint32_t*)xa)[(long)node * 32 + l] =
        (uint32_t)f2bf(a0) | ((uint32_t)f2bf(a1) << 16);
}

// ---------------- 256-col aggregation: half-wave/node, uint4 rows ----------------
__device__ __forceinline__ void fma8(float* acc, float w, uint4 v) {
    acc[0] += w * bf2f((uint16_t)(v.x & 0xffff));
    acc[1] += w * bf2f((uint16_t)(v.x >> 16));
    acc[2] += w * bf2f((uint16_t)(v.y & 0xffff));
    acc[3] += w * bf2f((uint16_t)(v.y >> 16));
    acc[4] += w * bf2f((uint16_t)(v.z & 0xffff));
    acc[5] += w * bf2f((uint16_t)(v.z >> 16));
    acc[6] += w * bf2f((uint16_t)(v.w & 0xffff));
    acc[7] += w * bf2f((uint16_t)(v.w >> 16));
}

__global__ __launch_bounds__(256) void k_aggb(const uint16_t* __restrict__ hw,
                                              const float* __restrict__ dinv,
                                              const int* __restrict__ count,
                                              const uint2* __restrict__ adj,
                                              const float* __restrict__ bias,
                                              uint16_t* __restrict__ out, int n) {
    __shared__ uint2 sadj[8][32];
    int hv = threadIdx.x >> 5;
    int l = threadIdx.x & 31;
    int node = blockIdx.x * 8 + hv;
    if (node >= n) return;
    const uint4* hw4 = (const uint4*)hw;
    float di = dinv[node];
    float c2 = di * di;
    uint4 h = hw4[(long)node * 32 + l];
    float acc[8];
    acc[0] = c2 * bf2f((uint16_t)(h.x & 0xffff));
    acc[1] = c2 * bf2f((uint16_t)(h.x >> 16));
    acc[2] = c2 * bf2f((uint16_t)(h.y & 0xffff));
    acc[3] = c2 * bf2f((uint16_t)(h.y >> 16));
    acc[4] = c2 * bf2f((uint16_t)(h.z & 0xffff));
    acc[5] = c2 * bf2f((uint16_t)(h.z >> 16));
    acc[6] = c2 * bf2f((uint16_t)(h.w & 0xffff));
    acc[7] = c2 * bf2f((uint16_t)(h.w >> 16));
    int cnt = count[node];
    const uint2* row = adj + ((long)node << 6);
    for (int base = 0; base < cnt; base += 32) {
        int m = cnt - base; if (m > 32) m = 32;
        if (l < m) {
            uint2 a = row[base + l];
            float w = __uint_as_float(a.y) * dinv[a.x] * di;
            uint2 p; p.x = a.x; p.y = __float_as_uint(w);
            sadj[hv][l] = p;
        }
        int t = 0;
        for (; t + 4 <= m; t += 4) {
            uint2 e0 = sadj[hv][t], e1 = sadj[hv][t + 1], e2 = sadj[hv][t + 2], e3 = sadj[hv][t + 3];
            uint4 v0 = hw4[(long)e0.x * 32 + l];
            uint4 v1 = hw4[(long)e1.x * 32 + l];
            uint4 v2 = hw4[(long)e2.x * 32 + l];
            uint4 v3 = hw4[(long)e3.x * 32 + l];
            fma8(acc, __uint_as_float(e0.y), v0);
            fma8(acc, __uint_as_float(e1.y), v1);
            fma8(acc, __uint_as_float(e2.y), v2);
            fma8(acc, __uint_as_float(e3.y), v3);
        }
        for (; t < m; t++) {
            uint2 e0 = sadj[hv][t];
            uint4 v0 = hw4[(long)e0.x * 32 + l];
            fma8(acc, __uint_as_float(e0.y), v0);
        }
    }
    float4 ba = ((const float4*)bias)[l * 2];
    float4 bb = ((const float4*)bias)[l * 2 + 1];
    acc[0] += ba.x; acc[1] += ba.y; acc[2] += ba.z; acc[3] += ba.w;
    acc[4] += bb.x; acc[5] += bb.y; acc[6] += bb.z; acc[7] += bb.w;
#pragma unroll
    for (int k = 0; k < 8; k++) acc[k] = acc[k] > 0.f ? acc[k] : NEG * acc[k];
    uint4 o;
    o.x = (uint32_t)f2bf(acc[0]) | ((uint32_t)f2bf(acc[1]) << 16);
    o.y = (uint32_t)f2bf(acc[2]) | ((uint32_t)f2bf(acc[3]) << 16);
    o.z = (uint32_t)f2bf(acc[4]) | ((uint32_t)f2bf(acc[5]) << 16);
    o.w = (uint32_t)f2bf(acc[6]) | ((uint32_t)f2bf(acc[7]) << 16);
    ((uint4*)out)[(long)node * 32 + l] = o;
}

// ---------------- bf16 MFMA GEMM (plain A) ----------------
__global__ __launch_bounds__(256) void k_mgemm(const uint16_t* __restrict__ A,
                                               const uint16_t* __restrict__ Bt,
                                               float* __restrict__ part,
                                               uint16_t* __restrict__ outb,
                                               const float* __restrict__ bias,
                                               int M, int K, int Kc, int act) {
    __shared__ uint16_t As[128 * 40];
    __shared__ uint16_t Bs[128 * 40];
    int tid = threadIdx.x;
    int lane = tid & 63, wv = tid >> 6;
    int quad = lane >> 4, l15 = lane & 15;
    int row0 = blockIdx.y * 128, col0 = blockIdx.x * 128;
    int kbeg = blockIdx.z * Kc;
    int kend = kbeg + Kc; if (kend > K) kend = K;
    int arow = (wv >> 1) * 64;
    int bcol = (wv & 1) * 64;

    f32x4 acc[4][4];
#pragma unroll
    for (int i = 0; i < 4; i++)
#pragma unroll
        for (int j = 0; j < 4; j++) acc[i][j] = (f32x4){0.f, 0.f, 0.f, 0.f};

    for (int kc = kbeg; kc < kend; kc += 32) {
#pragma unroll
        for (int i = 0; i < 2; i++) {
            int idx = tid + i * 256;
            int r = idx >> 2, cq = idx & 3;
            uint4 va = *(const uint4*)(A + (long)(row0 + r) * K + kc + cq * 8);
            *(uint4*)(&As[r * 40 + cq * 8]) = va;
            uint4 vb = *(const uint4*)(Bt + (long)(col0 + r) * K + kc + cq * 8);
            *(uint4*)(&Bs[r * 40 + cq * 8]) = vb;
        }
        __syncthreads();
        bf16x8 af[4], bfr[4];
#pragma unroll
        for (int i = 0; i < 4; i++)
            af[i] = __builtin_bit_cast(bf16x8,
                *(const uint4*)(&As[(arow + i * 16 + l15) * 40 + quad * 8]));
#pragma unroll
        for (int j = 0; j < 4; j++)
            bfr[j] = __builtin_bit_cast(bf16x8,
                *(const uint4*)(&Bs[(bcol + j * 16 + l15) * 40 + quad * 8]));
#pragma unroll
        for (int i = 0; i < 4; i++)
#pragma unroll
            for (int j = 0; j < 4; j++)
                acc[i][j] = __builtin_amdgcn_mfma_f32_16x16x32_bf16(af[i], bfr[j], acc[i][j], 0, 0, 0);
        __syncthreads();
    }

#pragma unroll
    for (int i = 0; i < 4; i++)
#pragma unroll
        for (int j = 0; j < 4; j++) {
            int row = row0 + arow + i * 16 + quad * 4;
            int col = col0 + bcol + j * 16 + l15;
#pragma unroll
            for (int reg = 0; reg < 4; reg++) {
                float v = acc[i][j][reg];
                long o = (long)(row + reg) * HID + col;
                if (part) part[(long)blockIdx.z * M * HID + o] = v;
                else {
                    if (bias) v += bias[col];
                    if (act) v = v > 0.f ? v : NEG * v;
                    outb[o] = f2bf(v);
                }
            }
        }
}

// ---------------- bf16 MFMA GEMM, VIRTUAL flat A (mlp0) ----------------
__global__ __launch_bounds__(256) void k_mgemm_flat(const uint16_t* __restrict__ h2,
                                                    const uint16_t* __restrict__ x64,
                                                    const uint16_t* __restrict__ Bt,
                                                    float* __restrict__ part,
                                                    int M, int Kc) {
    __shared__ uint16_t As[128 * 40];
    __shared__ uint16_t Bs[128 * 40];
    int tid = threadIdx.x;
    int lane = tid & 63, wv = tid >> 6;
    int quad = lane >> 4, l15 = lane & 15;
    int row0 = blockIdx.y * 128, col0 = blockIdx.x * 128;
    int kbeg = blockIdx.z * Kc;
    int kend = kbeg + Kc; if (kend > FLATP2) kend = FLATP2;
    int arow = (wv >> 1) * 64;
    int bcol = (wv & 1) * 64;

    f32x4 acc[4][4];
#pragma unroll
    for (int i = 0; i < 4; i++)
#pragma unroll
        for (int j = 0; j < 4; j++) acc[i][j] = (f32x4){0.f, 0.f, 0.f, 0.f};

    for (int kc = kbeg; kc < kend; kc += 32) {
#pragma unroll
        for (int i = 0; i < 2; i++) {
            int idx = tid + i * 256;
            int r = idx >> 2, cq = idx & 3;
            int gk = kc + cq * 8;
            int m = gk / PERM2;
            int k2 = gk - m * PERM2;
            long node = (long)(row0 + r) * MACH + m;
            uint4 va = (k2 < HID)
                ? *(const uint4*)(h2 + node * HID + k2)
                : *(const uint4*)(x64 + node * 64 + (k2 - HID));
            *(uint4*)(&As[r * 40 + cq * 8]) = va;
            uint4 vb = *(const uint4*)(Bt + (long)(col0 + r) * FLATP2 + gk);
            *(uint4*)(&Bs[r * 40 + cq * 8]) = vb;
        }
        __syncthreads();
        bf16x8 af[4], bfr[4];
#pragma unroll
        for (int i = 0; i < 4; i++)
            af[i] = __builtin_bit_cast(bf16x8,
                *(const uint4*)(&As[(arow + i * 16 + l15) * 40 + quad * 8]));
#pragma unroll
        for (int j = 0; j < 4; j++)
            bfr[j] = __builtin_bit_cast(bf16x8,
                *(const uint4*)(&Bs[(bcol + j * 16 + l15) * 40 + quad * 8]));
#pragma unroll
        for (int i = 0; i < 4; i++)
#pragma unroll
            for (int j = 0; j < 4; j++)
                acc[i][j] = __builtin_amdgcn_mfma_f32_16x16x32_bf16(af[i], bfr[j], acc[i][j], 0, 0, 0);
        __syncthreads();
    }

#pragma unroll
    for (int i = 0; i < 4; i++)
#pragma unroll
        for (int j = 0; j < 4; j++) {
            int row = row0 + arow + i * 16 + quad * 4;
            int col = col0 + bcol + j * 16 + l15;
#pragma unroll
            for (int reg = 0; reg < 4; reg++)
                part[(long)blockIdx.z * M * HID + (long)(row + reg) * HID + col] = acc[i][j][reg];
        }
}

// ---------------- fused tail: reduce(part)+bf0+lrelu -> mlp1 -> mlp2 -> out ------
#define S0 8
__global__ __launch_bounds__(256) void k_tail(const float* __restrict__ part,
                                              const float* __restrict__ bf0,
                                              const uint16_t* __restrict__ Wf1t,
                                              const float* __restrict__ bf1,
                                              const uint16_t* __restrict__ Wf2t,
                                              const float* __restrict__ bf2,
                                              const float* __restrict__ Wo,
                                              const float* __restrict__ bo,
                                              void* out, const int* flags, int MN) {
    __shared__ uint16_t z0s[16 * 256];
    __shared__ uint16_t z1s[16 * 256];
    __shared__ uint16_t z2s[16 * 256];
    int tid = threadIdx.x;
    int lane = tid & 63, wv = tid >> 6;
    int quad = lane >> 4, l15 = lane & 15;
    int rows0 = blockIdx.x * 16;
    int nw = wv * 64;

    // stage 0: reduce split-K partials for this block's 16 rows -> LDS
    for (int i = tid; i < 16 * 256; i += 256) {
        int rr = i >> 8, cc = i & 255;
        long idx = (long)(rows0 + rr) * HID + cc;
        float v = 0.f;
#pragma unroll
        for (int s = 0; s < S0; s++) v += part[(long)s * MN + idx];
        v += bf0[cc];
        v = v > 0.f ? v : NEG * v;
        z0s[i] = f2bf(v);
    }
    __syncthreads();

    // layer 1: z1 = lrelu(z0 @ Wf1t^T + bf1)
    {
        f32x4 acc[4];
#pragma unroll
        for (int j = 0; j < 4; j++) acc[j] = (f32x4){0.f, 0.f, 0.f, 0.f};
        for (int kc = 0; kc < HID; kc += 32) {
            bf16x8 a = __builtin_bit_cast(bf16x8,
                *(const uint4*)(&z0s[l15 * 256 + kc + quad * 8]));
#pragma unroll
            for (int j = 0; j < 4; j++) {
                bf16x8 b = __builtin_bit_cast(bf16x8,
                    *(const uint4*)(Wf1t + (long)(nw + j * 16 + l15) * HID + kc + quad * 8));
                acc[j] = __builtin_amdgcn_mfma_f32_16x16x32_bf16(a, b, acc[j], 0, 0, 0);
            }
        }
#pragma unroll
        for (int j = 0; j < 4; j++) {
            int col = nw + j * 16 + l15;
            float bj = bf1[col];
#pragma unroll
            for (int reg = 0; reg < 4; reg++) {
                float v = acc[j][reg] + bj;
                v = v > 0.f ? v : NEG * v;
                z1s[(quad * 4 + reg) * 256 + col] = f2bf(v);
            }
        }
    }
    __syncthreads();

    // layer 2: z2 = lrelu(z1 @ Wf2t^T + bf2)
    {
        f32x4 acc[4];
#pragma unroll
        for (int j = 0; j < 4; j++) acc[j] = (f32x4){0.f, 0.f, 0.f, 0.f};
        for (int kc = 0; kc < HID; kc += 32) {
            bf16x8 a = __builtin_bit_cast(bf16x8,
                *(const uint4*)(&z1s[l15 * 256 + kc + quad * 8]));
#pragma unroll
            for (int j = 0; j < 4; j++) {
                bf16x8 b = __builtin_bit_cast(bf16x8,
                    *(const uint4*)(Wf2t + (long)(nw + j * 16 + l15) * HID + kc + quad * 8));
                acc[j] = __builtin_amdgcn_mfma_f32_16x16x32_bf16(a, b, acc[j], 0, 0, 0);
            }
        }
#pragma unroll
        for (int j = 0; j < 4; j++) {
            int col = nw + j * 16 + l15;
            float bj = bf2[col];
#pragma unroll
            for (int reg = 0; reg < 4; reg++) {
                float v = acc[j][reg] + bj;
                v = v > 0.f ? v : NEG * v;
                z2s[(quad * 4 + reg) * 256 + col] = f2bf(v);
            }
        }
    }
    __syncthreads();

    // output head
    if (tid < 64) {
        int r = tid >> 2, o = tid & 3;
        float acc = bo[o];
        for (int k = 0; k < HID; k++)
            acc += bf2f(z2s[r * 256 + k]) * Wo[k * 4 + o];
        long idx = (long)(rows0 + r) * 4 + o;
        if (flags[0]) ((uint16_t*)out)[idx] = f2bf(acc);
        else          ((float*)out)[idx] = acc;
    }
}

// ---------------- host ----------------
extern "C" void kernel_launch(void* const* d_in, const int* in_sizes, int n_in,
                              void* d_out, int out_size, void* d_ws, size_t ws_size,
                              hipStream_t stream) {
    const int N  = in_sizes[0] / FEA;   // 45056
    const int E  = in_sizes[2];         // 720896
    const int Bn = N / MACH;            // 2048
    const int Kc0 = 896;                // ceil(7040/896)=8 K-slices

    char* ws = (char*)d_ws;
    size_t off = 0;
    auto alloc = [&](size_t bytes) -> char* {
        char* p = ws + off;
        off = (off + bytes + 255) & ~(size_t)255;
        return p;
    };

    int*      flags  = (int*)     alloc(64);
    uint16_t* x64    = (uint16_t*)alloc((size_t)N * 64 * 2);
    uint16_t* xa     = (uint16_t*)alloc((size_t)N * 64 * 2);
    uint16_t* W1t    = (uint16_t*)alloc((size_t)HID * 64 * 2);
    uint16_t* W2t    = (uint16_t*)alloc((size_t)HID * HID * 2);
    uint16_t* Wf0t   = (uint16_t*)alloc((size_t)HID * FLATP2 * 2);
    uint16_t* Wf1t   = (uint16_t*)alloc((size_t)HID * HID * 2);
    uint16_t* Wf2t   = (uint16_t*)alloc((size_t)HID * HID * 2);
    float*    b1     = (float*)   alloc(HID * 4);
    float*    b2     = (float*)   alloc(HID * 4);
    float*    bf0    = (float*)   alloc(HID * 4);
    float*    bf1    = (float*)   alloc(HID * 4);
    float*    bf2    = (float*)   alloc(HID * 4);
    float*    Wo     = (float*)   alloc((size_t)HID * 4 * 4);
    float*    bo     = (float*)   alloc(4 * 4);
    int*      count  = (int*)     alloc((size_t)N * 4);
    uint2*    adj    = (uint2*)   alloc((size_t)N * BCAP * 8);   // 23 MB buckets
    float*    dinv   = (float*)   alloc((size_t)N * 4);
    uint16_t* P      = (uint16_t*)alloc((size_t)N * HID * 2);    // h1 / h2
    uint16_t* Q      = (uint16_t*)alloc((size_t)N * HID * 2);    // hw
    float*    part   = (float*)   alloc((size_t)S0 * Bn * HID * 4);
    (void)ws_size; (void)n_in; (void)out_size;

    // 1. detect + zero count
    k_detect_init<<<(N + 255) / 256, 256, 0, stream>>>(
        (const uint32_t*)d_in[2], (const uint32_t*)d_in[1], flags, count, N);

    // 2. conversions (x64 + small fp32), merged weight transposes
    Cvt8 c8{};
    const void* s8[7] = { d_in[4], d_in[6], d_in[8], d_in[10], d_in[12], d_in[13], d_in[14] };
    float* d8[7] = { b1, b2, bf0, bf1, bf2, Wo, bo };
    long n8[7] = { HID, HID, HID, HID, HID, (long)HID * 4, 4 };
    c8.cnt = 7;
    c8.prefix[0] = 0;
    for (int t = 0; t < 7; t++) { c8.src[t] = s8[t]; c8.dst[t] = d8[t]; c8.prefix[t + 1] = c8.prefix[t] + n8[t]; }
    c8.prefix[8] = c8.prefix[7];
    k_cvt_all<<<2048, 256, 0, stream>>>(d_in[0], x64, N, c8, flags);
    PrepW pw{};
    pw.wf0 = d_in[7]; pw.wf0t = Wf0t;
    pw.src3[0] = d_in[5];  pw.dst3[0] = W2t;
    pw.src3[1] = d_in[9];  pw.dst3[1] = Wf1t;
    pw.src3[2] = d_in[11]; pw.dst3[2] = Wf2t;
    pw.w1 = d_in[3]; pw.w1t = W1t;
    k_prep<<<492, 256, 0, stream>>>(pw, flags);

    // 3. bucket-CSR scatter (one atomic pass) + dinv
    k_scatter<<<(E / 2 + 255) / 256, 256, 0, stream>>>(d_in[1], d_in[2], count, adj, E, flags);
    k_rowsum<<<(N + 255) / 256, 256, 0, stream>>>(count, adj, dinv, N);

    // 4. GCN layer 1: xa = agg(x64) ; h1 = lrelu(xa @ W1t + b1)
    k_aggx<<<(N + 7) / 8, 256, 0, stream>>>(x64, dinv, count, adj, xa, N);
    k_mgemm<<<dim3(2, N / 128, 1), 256, 0, stream>>>(xa, W1t, nullptr, P, b1, N, 64, 64, 1);

    // 5. GCN layer 2: hw = h1 @ W2t ; h2 = agg(hw) + b2, lrelu
    k_mgemm<<<dim3(2, N / 128, 1), 256, 0, stream>>>(P, W2t, nullptr, Q, nullptr, N, HID, HID, 0);
    k_aggb<<<(N + 7) / 8, 256, 0, stream>>>(Q, dinv, count, adj, b2, P, N);

    // 6. mlp0: virtual-flat split-K (S=8, Kc=896) -> fp32 partials
    k_mgemm_flat<<<dim3(2, Bn / 128, S0), 256, 0, stream>>>(P, x64, Wf0t, part, Bn, Kc0);

    // 7. fused tail: reduce + mlp1 + mlp2 + out
    k_tail<<<Bn / 16, 256, 0, stream>>>(part, bf0, Wf1t, bf1, Wf2t, bf2, Wo, bo,
                                        d_out, flags, Bn * HID);
}

// Round 7
// 317.222 us; speedup vs baseline: 5.0389x; 1.0140x over previous
//
#include <hip/hip_runtime.h>
#include <stdint.h>

#define FEA 60
#define HID 256
#define MACH 22
#define PERM 316             // HID + FEA (reference layout)
#define PERM2 320            // padded per-machine stride (mult of 8)
#define FLATP2 (MACH * PERM2)   // 7040
#define NEG 0.01f
#define BCAP 64              // adjacency bucket capacity (max deg of ~Poisson(16) ≲ 45)
#define S0 16                // mlp0 K-slices (Kc=448)
#define KC0 448

typedef __bf16 bf16x8 __attribute__((ext_vector_type(8)));
typedef float f32x4 __attribute__((ext_vector_type(4)));

__device__ __forceinline__ float bf2f(uint16_t u) {
    return __uint_as_float(((uint32_t)u) << 16);
}
__device__ __forceinline__ uint16_t f2bf(float f) {   // RNE
    uint32_t x = __float_as_uint(f);
    return (uint16_t)((x + 0x7fffu + ((x >> 16) & 1u)) >> 16);
}

// ---------------- detect dtypes + zero count + zero z0acc ----------------
// flags[0]=1 if float tensors bf16 ; flags[1]=1 if edge_index int64
// grid 2048x256: thread i zeroes z0acc[i] (2048*256 elems) and count[i<N]
__global__ void k_detect_init(const uint32_t* ew_w, const uint32_t* ei_w, int* flags,
                              int* count, float* z0acc, int n) {
    int i = blockIdx.x * blockDim.x + threadIdx.x;
    if (i < n) count[i] = 0;
    z0acc[i] = 0.f;
    if (blockIdx.x == 0) {
        __shared__ int c15, onz;
        if (threadIdx.x == 0) { c15 = 0; onz = 0; }
        __syncthreads();
        int a = 0, b = 0;
        for (int k = threadIdx.x; k < 1024; k += 256) {
            if (ew_w[k] & 0x8000u) a++;
            if (ei_w[2 * k + 1] != 0u) b++;
        }
        atomicAdd(&c15, a); atomicAdd(&onz, b);
        __syncthreads();
        if (threadIdx.x == 0) {
            flags[0] = (c15 <= 100) ? 1 : 0;
            flags[1] = (onz < 8) ? 1 : 0;
        }
    }
}

// ---------------- mega prep: cvt + weight transposes + edge scatter ----------------
// blocks [0,1024): x64 conversion + small fp32 tensors (grid-stride over that range)
// blocks [1024,1516): weight transposes (Wf0 440, three 256x256 48, W1 4)
// blocks [1516,2924): bucket-CSR scatter, 2 edges/thread
struct PrepAll {
    // cvt
    const void* xsrc; uint16_t* x64;
    const void* src8[8]; float* dst8[8]; long prefix[9]; int cnt8;
    // transposes
    const void* wf0; uint16_t* wf0t;
    const void* src3[3]; uint16_t* dst3[3];
    const void* w1; uint16_t* w1t;
    // scatter
    const void* ei; const void* ew; int* count; uint2* adj; int E;
    int n;
};

#define NB_CVT 1024
#define NB_TR  492

__global__ __launch_bounds__(256) void k_prep_all(PrepAll a, const int* flags) {
    int isbf = flags[0];
    int b = blockIdx.x;
    int t = threadIdx.x;
    if (b < NB_CVT) {
        // ---- conversions ----
        long nx = (long)a.n * 64;
        long total = nx + a.prefix[a.cnt8];
        for (long i = (long)b * 256 + t; i < total; i += (long)NB_CVT * 256) {
            if (i < nx) {
                int col = (int)(i & 63);
                long row = i >> 6;
                uint16_t v = 0;
                if (col < FEA) {
                    long s = row * FEA + col;
                    v = isbf ? ((const uint16_t*)a.xsrc)[s] : f2bf(((const float*)a.xsrc)[s]);
                }
                a.x64[i] = v;
            } else {
                long ii = i - nx;
                int tt = 0;
                while (ii >= a.prefix[tt + 1]) tt++;
                long j = ii - a.prefix[tt];
                a.dst8[tt][j] = isbf ? bf2f(((const uint16_t*)a.src8[tt])[j])
                                     : ((const float*)a.src8[tt])[j];
            }
        }
    } else if (b < NB_CVT + NB_TR) {
        // ---- weight transposes ----
        __shared__ uint16_t s[64][65];
        int bb = b - NB_CVT;
        if (bb < 440) {
            int g0 = (bb >> 2) * 64, n0 = (bb & 3) * 64;
#pragma unroll
            for (int i = 0; i < 16; i++) {
                int idx = t + i * 256;
                int gg = idx >> 6, nn = idx & 63;
                int gk = g0 + gg;
                int m = gk / PERM2;
                int k2 = gk - m * PERM2;
                uint16_t v = 0;
                if (k2 < PERM) {
                    long off = (long)(m * PERM + k2) * HID + n0 + nn;
                    v = isbf ? ((const uint16_t*)a.wf0)[off] : f2bf(((const float*)a.wf0)[off]);
                }
                s[gg][nn] = v;
            }
            __syncthreads();
#pragma unroll
            for (int i = 0; i < 16; i++) {
                int idx = t + i * 256;
                int nn = idx >> 6, gg = idx & 63;
                a.wf0t[(long)(n0 + nn) * FLATP2 + g0 + gg] = s[gg][nn];
            }
        } else if (bb < 488) {
            int idx0 = bb - 440;
            int z = idx0 >> 4, r = idx0 & 15;
            int k0 = (r >> 2) * 64, n0 = (r & 3) * 64;
            const void* W = a.src3[z];
            uint16_t* Wt = a.dst3[z];
#pragma unroll
            for (int i = 0; i < 16; i++) {
                int idx = t + i * 256;
                int kk = idx >> 6, nn = idx & 63;
                long off = (long)(k0 + kk) * HID + n0 + nn;
                s[kk][nn] = isbf ? ((const uint16_t*)W)[off] : f2bf(((const float*)W)[off]);
            }
            __syncthreads();
#pragma unroll
            for (int i = 0; i < 16; i++) {
                int idx = t + i * 256;
                int nn = idx >> 6, kk = idx & 63;
                Wt[(long)(n0 + nn) * HID + k0 + kk] = s[kk][nn];
            }
        } else {
            int n0 = (bb - 488) * 64;
#pragma unroll
            for (int i = 0; i < 16; i++) {
                int idx = t + i * 256;
                int kk = idx >> 6, nn = idx & 63;
                uint16_t v = 0;
                if (kk < FEA) {
                    long off = (long)kk * HID + n0 + nn;
                    v = isbf ? ((const uint16_t*)a.w1)[off] : f2bf(((const float*)a.w1)[off]);
                }
                s[kk][nn] = v;
            }
            __syncthreads();
#pragma unroll
            for (int i = 0; i < 16; i++) {
                int idx = t + i * 256;
                int nn = idx >> 6, kk = idx & 63;
                a.w1t[(long)(n0 + nn) * 64 + kk] = s[kk][nn];
            }
        }
    } else {
        // ---- bucket-CSR scatter ----
        int e0 = ((b - NB_CVT - NB_TR) * 256 + t) * 2;
        int E = a.E;
        if (e0 >= E) return;
        int i64 = flags[1];
        int r0, r1 = -1, c0, c1 = -1;
        if (i64) {
            const long long* pr = (const long long*)a.ei + e0;
            const long long* pc = (const long long*)a.ei + E + e0;
            r0 = (int)pr[0]; c0 = (int)pc[0];
            if (e0 + 1 < E) { r1 = (int)pr[1]; c1 = (int)pc[1]; }
        } else {
            const int* pr = (const int*)a.ei + e0;
            const int* pc = (const int*)a.ei + E + e0;
            r0 = pr[0]; c0 = pc[0];
            if (e0 + 1 < E) { r1 = pr[1]; c1 = pc[1]; }
        }
        float w0, w1 = 0.f;
        if (isbf) {
            uint32_t ww = ((const uint32_t*)a.ew)[e0 >> 1];
            w0 = bf2f((uint16_t)(ww & 0xffff));
            w1 = bf2f((uint16_t)(ww >> 16));
        } else {
            float2 f = ((const float2*)a.ew)[e0 >> 1];
            w0 = f.x; w1 = f.y;
        }
        int p0 = atomicAdd(&a.count[c0], 1);
        uint2 v0; v0.x = (uint32_t)r0; v0.y = __float_as_uint(w0);
        a.adj[((long)c0 << 6) + p0] = v0;
        if (c1 >= 0) {
            int p1 = atomicAdd(&a.count[c1], 1);
            uint2 v1; v1.x = (uint32_t)r1; v1.y = __float_as_uint(w1);
            a.adj[((long)c1 << 6) + p1] = v1;
        }
    }
}

// dinv = 1/sqrt(1 + row-sum of raw ew) over bucket
__global__ void k_rowsum(const int* count, const uint2* adj, float* dinv, int n) {
    int i = blockIdx.x * blockDim.x + threadIdx.x;
    if (i >= n) return;
    int cnt = count[i];
    const uint2* row = adj + ((long)i << 6);
    double d = 1.0;
    for (int p = 0; p < cnt; p++) d += (double)__uint_as_float(row[p].y);
    dinv[i] = (float)(1.0 / sqrt(d));
}

// ---------------- layer-1 pre-aggregation on x64 [N][64] ----------------
__global__ __launch_bounds__(256) void k_aggx(const uint16_t* __restrict__ x64,
                                              const float* __restrict__ dinv,
                                              const int* __restrict__ count,
                                              const uint2* __restrict__ adj,
                                              uint16_t* __restrict__ xa, int n) {
    __shared__ uint2 sadj[8][32];
    int hv = threadIdx.x >> 5;
    int l = threadIdx.x & 31;
    int node = blockIdx.x * 8 + hv;
    if (node >= n) return;
    const uint32_t* xu = (const uint32_t*)x64;
    float di = dinv[node];
    float c2 = di * di;
    uint32_t h = xu[(long)node * 32 + l];
    float a0 = c2 * bf2f((uint16_t)(h & 0xffff));
    float a1 = c2 * bf2f((uint16_t)(h >> 16));
    int cnt = count[node];
    const uint2* row = adj + ((long)node << 6);
    for (int base = 0; base < cnt; base += 32) {
        int m = cnt - base; if (m > 32) m = 32;
        if (l < m) {
            uint2 a = row[base + l];
            float w = __uint_as_float(a.y) * dinv[a.x] * di;
            uint2 p; p.x = a.x; p.y = __float_as_uint(w);
            sadj[hv][l] = p;
        }
        int t = 0;
        for (; t + 4 <= m; t += 4) {
            uint2 e0 = sadj[hv][t], e1 = sadj[hv][t + 1], e2 = sadj[hv][t + 2], e3 = sadj[hv][t + 3];
            uint32_t v0 = xu[(long)e0.x * 32 + l];
            uint32_t v1 = xu[(long)e1.x * 32 + l];
            uint32_t v2 = xu[(long)e2.x * 32 + l];
            uint32_t v3 = xu[(long)e3.x * 32 + l];
            float w0 = __uint_as_float(e0.y), w1 = __uint_as_float(e1.y);
            float w2 = __uint_as_float(e2.y), w3 = __uint_as_float(e3.y);
            a0 += w0 * bf2f((uint16_t)(v0 & 0xffff)); a1 += w0 * bf2f((uint16_t)(v0 >> 16));
            a0 += w1 * bf2f((uint16_t)(v1 & 0xffff)); a1 += w1 * bf2f((uint16_t)(v1 >> 16));
            a0 += w2 * bf2f((uint16_t)(v2 & 0xffff)); a1 += w2 * bf2f((uint16_t)(v2 >> 16));
            a0 += w3 * bf2f((uint16_t)(v3 & 0xffff)); a1 += w3 * bf2f((uint16_t)(v3 >> 16));
        }
        for (; t < m; t++) {
            uint2 e0 = sadj[hv][t];
            uint32_t v0 = xu[(long)e0.x * 32 + l];
            float w0 = __uint_as_float(e0.y);
            a0 += w0 * bf2f((uint16_t)(v0 & 0xffff));
            a1 += w0 * bf2f((uint16_t)(v0 >> 16));
        }
    }
    ((uint32_t*)xa)[(long)node * 32 + l] =
        (uint32_t)f2bf(a0) | ((uint32_t)f2bf(a1) << 16);
}

// ---------------- 256-col aggregation: half-wave/node, uint4 rows ----------------
__device__ __forceinline__ void fma8(float* acc, float w, uint4 v) {
    acc[0] += w * bf2f((uint16_t)(v.x & 0xffff));
    acc[1] += w * bf2f((uint16_t)(v.x >> 16));
    acc[2] += w * bf2f((uint16_t)(v.y & 0xffff));
    acc[3] += w * bf2f((uint16_t)(v.y >> 16));
    acc[4] += w * bf2f((uint16_t)(v.z & 0xffff));
    acc[5] += w * bf2f((uint16_t)(v.z >> 16));
    acc[6] += w * bf2f((uint16_t)(v.w & 0xffff));
    acc[7] += w * bf2f((uint16_t)(v.w >> 16));
}

__global__ __launch_bounds__(256) void k_aggb(const uint16_t* __restrict__ hw,
                                              const float* __restrict__ dinv,
                                              const int* __restrict__ count,
                                              const uint2* __restrict__ adj,
                                              const float* __restrict__ bias,
                                              uint16_t* __restrict__ out, int n) {
    __shared__ uint2 sadj[8][32];
    int hv = threadIdx.x >> 5;
    int l = threadIdx.x & 31;
    int node = blockIdx.x * 8 + hv;
    if (node >= n) return;
    const uint4* hw4 = (const uint4*)hw;
    float di = dinv[node];
    float c2 = di * di;
    uint4 h = hw4[(long)node * 32 + l];
    float acc[8];
    acc[0] = c2 * bf2f((uint16_t)(h.x & 0xffff));
    acc[1] = c2 * bf2f((uint16_t)(h.x >> 16));
    acc[2] = c2 * bf2f((uint16_t)(h.y & 0xffff));
    acc[3] = c2 * bf2f((uint16_t)(h.y >> 16));
    acc[4] = c2 * bf2f((uint16_t)(h.z & 0xffff));
    acc[5] = c2 * bf2f((uint16_t)(h.z >> 16));
    acc[6] = c2 * bf2f((uint16_t)(h.w & 0xffff));
    acc[7] = c2 * bf2f((uint16_t)(h.w >> 16));
    int cnt = count[node];
    const uint2* row = adj + ((long)node << 6);
    for (int base = 0; base < cnt; base += 32) {
        int m = cnt - base; if (m > 32) m = 32;
        if (l < m) {
            uint2 a = row[base + l];
            float w = __uint_as_float(a.y) * dinv[a.x] * di;
            uint2 p; p.x = a.x; p.y = __float_as_uint(w);
            sadj[hv][l] = p;
        }
        int t = 0;
        for (; t + 4 <= m; t += 4) {
            uint2 e0 = sadj[hv][t], e1 = sadj[hv][t + 1], e2 = sadj[hv][t + 2], e3 = sadj[hv][t + 3];
            uint4 v0 = hw4[(long)e0.x * 32 + l];
            uint4 v1 = hw4[(long)e1.x * 32 + l];
            uint4 v2 = hw4[(long)e2.x * 32 + l];
            uint4 v3 = hw4[(long)e3.x * 32 + l];
            fma8(acc, __uint_as_float(e0.y), v0);
            fma8(acc, __uint_as_float(e1.y), v1);
            fma8(acc, __uint_as_float(e2.y), v2);
            fma8(acc, __uint_as_float(e3.y), v3);
        }
        for (; t < m; t++) {
            uint2 e0 = sadj[hv][t];
            uint4 v0 = hw4[(long)e0.x * 32 + l];
            fma8(acc, __uint_as_float(e0.y), v0);
        }
    }
    float4 ba = ((const float4*)bias)[l * 2];
    float4 bb = ((const float4*)bias)[l * 2 + 1];
    acc[0] += ba.x; acc[1] += ba.y; acc[2] += ba.z; acc[3] += ba.w;
    acc[4] += bb.x; acc[5] += bb.y; acc[6] += bb.z; acc[7] += bb.w;
#pragma unroll
    for (int k = 0; k < 8; k++) acc[k] = acc[k] > 0.f ? acc[k] : NEG * acc[k];
    uint4 o;
    o.x = (uint32_t)f2bf(acc[0]) | ((uint32_t)f2bf(acc[1]) << 16);
    o.y = (uint32_t)f2bf(acc[2]) | ((uint32_t)f2bf(acc[3]) << 16);
    o.z = (uint32_t)f2bf(acc[4]) | ((uint32_t)f2bf(acc[5]) << 16);
    o.w = (uint32_t)f2bf(acc[6]) | ((uint32_t)f2bf(acc[7]) << 16);
    ((uint4*)out)[(long)node * 32 + l] = o;
}

// ---------------- bf16 MFMA GEMM (plain A) ----------------
__global__ __launch_bounds__(256) void k_mgemm(const uint16_t* __restrict__ A,
                                               const uint16_t* __restrict__ Bt,
                                               uint16_t* __restrict__ outb,
                                               const float* __restrict__ bias,
                                               int M, int K, int act) {
    __shared__ uint16_t As[128 * 40];
    __shared__ uint16_t Bs[128 * 40];
    int tid = threadIdx.x;
    int lane = tid & 63, wv = tid >> 6;
    int quad = lane >> 4, l15 = lane & 15;
    int row0 = blockIdx.y * 128, col0 = blockIdx.x * 128;
    int arow = (wv >> 1) * 64;
    int bcol = (wv & 1) * 64;

    f32x4 acc[4][4];
#pragma unroll
    for (int i = 0; i < 4; i++)
#pragma unroll
        for (int j = 0; j < 4; j++) acc[i][j] = (f32x4){0.f, 0.f, 0.f, 0.f};

    for (int kc = 0; kc < K; kc += 32) {
#pragma unroll
        for (int i = 0; i < 2; i++) {
            int idx = tid + i * 256;
            int r = idx >> 2, cq = idx & 3;
            uint4 va = *(const uint4*)(A + (long)(row0 + r) * K + kc + cq * 8);
            *(uint4*)(&As[r * 40 + cq * 8]) = va;
            uint4 vb = *(const uint4*)(Bt + (long)(col0 + r) * K + kc + cq * 8);
            *(uint4*)(&Bs[r * 40 + cq * 8]) = vb;
        }
        __syncthreads();
        bf16x8 af[4], bfr[4];
#pragma unroll
        for (int i = 0; i < 4; i++)
            af[i] = __builtin_bit_cast(bf16x8,
                *(const uint4*)(&As[(arow + i * 16 + l15) * 40 + quad * 8]));
#pragma unroll
        for (int j = 0; j < 4; j++)
            bfr[j] = __builtin_bit_cast(bf16x8,
                *(const uint4*)(&Bs[(bcol + j * 16 + l15) * 40 + quad * 8]));
#pragma unroll
        for (int i = 0; i < 4; i++)
#pragma unroll
            for (int j = 0; j < 4; j++)
                acc[i][j] = __builtin_amdgcn_mfma_f32_16x16x32_bf16(af[i], bfr[j], acc[i][j], 0, 0, 0);
        __syncthreads();
    }

#pragma unroll
    for (int i = 0; i < 4; i++)
#pragma unroll
        for (int j = 0; j < 4; j++) {
            int row = row0 + arow + i * 16 + quad * 4;
            int col = col0 + bcol + j * 16 + l15;
#pragma unroll
            for (int reg = 0; reg < 4; reg++) {
                float v = acc[i][j][reg];
                if (bias) v += bias[col];
                if (act) v = v > 0.f ? v : NEG * v;
                outb[(long)(row + reg) * HID + col] = f2bf(v);
            }
        }
}

// ---------------- bf16 MFMA GEMM, VIRTUAL flat A (mlp0), atomic epilogue ----------
__global__ __launch_bounds__(256) void k_mgemm_flat(const uint16_t* __restrict__ h2,
                                                    const uint16_t* __restrict__ x64,
                                                    const uint16_t* __restrict__ Bt,
                                                    float* __restrict__ z0acc,
                                                    int M) {
    __shared__ uint16_t As[128 * 40];
    __shared__ uint16_t Bs[128 * 40];
    int tid = threadIdx.x;
    int lane = tid & 63, wv = tid >> 6;
    int quad = lane >> 4, l15 = lane & 15;
    int row0 = blockIdx.y * 128, col0 = blockIdx.x * 128;
    int kbeg = blockIdx.z * KC0;
    int kend = kbeg + KC0; if (kend > FLATP2) kend = FLATP2;
    int arow = (wv >> 1) * 64;
    int bcol = (wv & 1) * 64;

    f32x4 acc[4][4];
#pragma unroll
    for (int i = 0; i < 4; i++)
#pragma unroll
        for (int j = 0; j < 4; j++) acc[i][j] = (f32x4){0.f, 0.f, 0.f, 0.f};

    for (int kc = kbeg; kc < kend; kc += 32) {
#pragma unroll
        for (int i = 0; i < 2; i++) {
            int idx = tid + i * 256;
            int r = idx >> 2, cq = idx & 3;
            int gk = kc + cq * 8;
            int m = gk / PERM2;
            int k2 = gk - m * PERM2;
            long node = (long)(row0 + r) * MACH + m;
            uint4 va = (k2 < HID)
                ? *(const uint4*)(h2 + node * HID + k2)
                : *(const uint4*)(x64 + node * 64 + (k2 - HID));
            *(uint4*)(&As[r * 40 + cq * 8]) = va;
            uint4 vb = *(const uint4*)(Bt + (long)(col0 + r) * FLATP2 + gk);
            *(uint4*)(&Bs[r * 40 + cq * 8]) = vb;
        }
        __syncthreads();
        bf16x8 af[4], bfr[4];
#pragma unroll
        for (int i = 0; i < 4; i++)
            af[i] = __builtin_bit_cast(bf16x8,
                *(const uint4*)(&As[(arow + i * 16 + l15) * 40 + quad * 8]));
#pragma unroll
        for (int j = 0; j < 4; j++)
            bfr[j] = __builtin_bit_cast(bf16x8,
                *(const uint4*)(&Bs[(bcol + j * 16 + l15) * 40 + quad * 8]));
#pragma unroll
        for (int i = 0; i < 4; i++)
#pragma unroll
            for (int j = 0; j < 4; j++)
                acc[i][j] = __builtin_amdgcn_mfma_f32_16x16x32_bf16(af[i], bfr[j], acc[i][j], 0, 0, 0);
        __syncthreads();
    }

#pragma unroll
    for (int i = 0; i < 4; i++)
#pragma unroll
        for (int j = 0; j < 4; j++) {
            int row = row0 + arow + i * 16 + quad * 4;
            int col = col0 + bcol + j * 16 + l15;
#pragma unroll
            for (int reg = 0; reg < 4; reg++)
                atomicAdd(&z0acc[(long)(row + reg) * HID + col], acc[i][j][reg]);
        }
}

// ---------------- fused tail: z0acc+bf0+lrelu -> mlp1 -> mlp2 -> out ------
__global__ __launch_bounds__(256) void k_tail(const float* __restrict__ z0acc,
                                              const float* __restrict__ bf0,
                                              const uint16_t* __restrict__ Wf1t,
                                              const float* __restrict__ bf1,
                                              const uint16_t* __restrict__ Wf2t,
                                              const float* __restrict__ bf2,
                                              const float* __restrict__ Wo,
                                              const float* __restrict__ bo,
                                              void* out, const int* flags) {
    __shared__ uint16_t z0s[16 * 256];
    __shared__ uint16_t z1s[16 * 256];
    __shared__ uint16_t z2s[16 * 256];
    int tid = threadIdx.x;
    int lane = tid & 63, wv = tid >> 6;
    int quad = lane >> 4, l15 = lane & 15;
    int rows0 = blockIdx.x * 16;
    int nw = wv * 64;

    // stage 0: bias + lrelu on accumulated mlp0 output -> LDS bf16
    for (int i = tid; i < 16 * 256; i += 256) {
        int rr = i >> 8, cc = i & 255;
        float v = z0acc[(long)(rows0 + rr) * HID + cc] + bf0[cc];
        v = v > 0.f ? v : NEG * v;
        z0s[i] = f2bf(v);
    }
    __syncthreads();

    // layer 1
    {
        f32x4 acc[4];
#pragma unroll
        for (int j = 0; j < 4; j++) acc[j] = (f32x4){0.f, 0.f, 0.f, 0.f};
        for (int kc = 0; kc < HID; kc += 32) {
            bf16x8 a = __builtin_bit_cast(bf16x8,
                *(const uint4*)(&z0s[l15 * 256 + kc + quad * 8]));
#pragma unroll
            for (int j = 0; j < 4; j++) {
                bf16x8 b = __builtin_bit_cast(bf16x8,
                    *(const uint4*)(Wf1t + (long)(nw + j * 16 + l15) * HID + kc + quad * 8));
                acc[j] = __builtin_amdgcn_mfma_f32_16x16x32_bf16(a, b, acc[j], 0, 0, 0);
            }
        }
#pragma unroll
        for (int j = 0; j < 4; j++) {
            int col = nw + j * 16 + l15;
            float bj = bf1[col];
#pragma unroll
            for (int reg = 0; reg < 4; reg++) {
                float v = acc[j][reg] + bj;
                v = v > 0.f ? v : NEG * v;
                z1s[(quad * 4 + reg) * 256 + col] = f2bf(v);
            }
        }
    }
    __syncthreads();

    // layer 2
    {
        f32x4 acc[4];
#pragma unroll
        for (int j = 0; j < 4; j++) acc[j] = (f32x4){0.f, 0.f, 0.f, 0.f};
        for (int kc = 0; kc < HID; kc += 32) {
            bf16x8 a = __builtin_bit_cast(bf16x8,
                *(const uint4*)(&z1s[l15 * 256 + kc + quad * 8]));
#pragma unroll
            for (int j = 0; j < 4; j++) {
                bf16x8 b = __builtin_bit_cast(bf16x8,
                    *(const uint4*)(Wf2t + (long)(nw + j * 16 + l15) * HID + kc + quad * 8));
                acc[j] = __builtin_amdgcn_mfma_f32_16x16x32_bf16(a, b, acc[j], 0, 0, 0);
            }
        }
#pragma unroll
        for (int j = 0; j < 4; j++) {
            int col = nw + j * 16 + l15;
            float bj = bf2[col];
#pragma unroll
            for (int reg = 0; reg < 4; reg++) {
                float v = acc[j][reg] + bj;
                v = v > 0.f ? v : NEG * v;
                z2s[(quad * 4 + reg) * 256 + col] = f2bf(v);
            }
        }
    }
    __syncthreads();

    // output head
    if (tid < 64) {
        int r = tid >> 2, o = tid & 3;
        float acc = bo[o];
        for (int k = 0; k < HID; k++)
            acc += bf2f(z2s[r * 256 + k]) * Wo[k * 4 + o];
        long idx = (long)(rows0 + r) * 4 + o;
        if (flags[0]) ((uint16_t*)out)[idx] = f2bf(acc);
        else          ((float*)out)[idx] = acc;
    }
}

// ---------------- host ----------------
extern "C" void kernel_launch(void* const* d_in, const int* in_sizes, int n_in,
                              void* d_out, int out_size, void* d_ws, size_t ws_size,
                              hipStream_t stream) {
    const int N  = in_sizes[0] / FEA;   // 45056
    const int E  = in_sizes[2];         // 720896
    const int Bn = N / MACH;            // 2048

    char* ws = (char*)d_ws;
    size_t off = 0;
    auto alloc = [&](size_t bytes) -> char* {
        char* p = ws + off;
        off = (off + bytes + 255) & ~(size_t)255;
        return p;
    };

    int*      flags  = (int*)     alloc(64);
    uint16_t* x64    = (uint16_t*)alloc((size_t)N * 64 * 2);
    uint16_t* xa     = (uint16_t*)alloc((size_t)N * 64 * 2);
    uint16_t* W1t    = (uint16_t*)alloc((size_t)HID * 64 * 2);
    uint16_t* W2t    = (uint16_t*)alloc((size_t)HID * HID * 2);
    uint16_t* Wf0t   = (uint16_t*)alloc((size_t)HID * FLATP2 * 2);
    uint16_t* Wf1t   = (uint16_t*)alloc((size_t)HID * HID * 2);
    uint16_t* Wf2t   = (uint16_t*)alloc((size_t)HID * HID * 2);
    float*    b1     = (float*)   alloc(HID * 4);
    float*    b2     = (float*)   alloc(HID * 4);
    float*    bf0    = (float*)   alloc(HID * 4);
    float*    bf1    = (float*)   alloc(HID * 4);
    float*    bf2    = (float*)   alloc(HID * 4);
    float*    Wo     = (float*)   alloc((size_t)HID * 4 * 4);
    float*    bo     = (float*)   alloc(4 * 4);
    int*      count  = (int*)     alloc((size_t)N * 4);
    uint2*    adj    = (uint2*)   alloc((size_t)N * BCAP * 8);   // 23 MB buckets
    float*    dinv   = (float*)   alloc((size_t)N * 4);
    uint16_t* P      = (uint16_t*)alloc((size_t)N * HID * 2);    // h1 / h2
    uint16_t* Q      = (uint16_t*)alloc((size_t)N * HID * 2);    // hw
    float*    z0acc  = (float*)   alloc((size_t)Bn * HID * 4);   // 2 MB fp32 accumulator
    (void)ws_size; (void)n_in; (void)out_size;

    // 1. detect + zero count + zero z0acc   (grid covers Bn*HID = 524288 threads)
    k_detect_init<<<(Bn * HID) / 256, 256, 0, stream>>>(
        (const uint32_t*)d_in[2], (const uint32_t*)d_in[1], flags, count, z0acc, N);

    // 2. mega-prep: conversions + weight transposes + edge scatter
    PrepAll pa{};
    pa.xsrc = d_in[0]; pa.x64 = x64;
    const void* s8[7] = { d_in[4], d_in[6], d_in[8], d_in[10], d_in[12], d_in[13], d_in[14] };
    float* d8[7] = { b1, b2, bf0, bf1, bf2, Wo, bo };
    long n8[7] = { HID, HID, HID, HID, HID, (long)HID * 4, 4 };
    pa.cnt8 = 7;
    pa.prefix[0] = 0;
    for (int t = 0; t < 7; t++) { pa.src8[t] = s8[t]; pa.dst8[t] = d8[t]; pa.prefix[t + 1] = pa.prefix[t] + n8[t]; }
    pa.prefix[8] = pa.prefix[7];
    pa.wf0 = d_in[7]; pa.wf0t = Wf0t;
    pa.src3[0] = d_in[5];  pa.dst3[0] = W2t;
    pa.src3[1] = d_in[9];  pa.dst3[1] = Wf1t;
    pa.src3[2] = d_in[11]; pa.dst3[2] = Wf2t;
    pa.w1 = d_in[3]; pa.w1t = W1t;
    pa.ei = d_in[1]; pa.ew = d_in[2]; pa.count = count; pa.adj = adj; pa.E = E;
    pa.n = N;
    int nb_sc = (E / 2 + 255) / 256;          // 1408
    k_prep_all<<<NB_CVT + NB_TR + nb_sc, 256, 0, stream>>>(pa, flags);

    // 3. dinv from buckets
    k_rowsum<<<(N + 255) / 256, 256, 0, stream>>>(count, adj, dinv, N);

    // 4. GCN layer 1: xa = agg(x64) ; h1 = lrelu(xa @ W1t + b1)
    k_aggx<<<(N + 7) / 8, 256, 0, stream>>>(x64, dinv, count, adj, xa, N);
    k_mgemm<<<dim3(2, N / 128), 256, 0, stream>>>(xa, W1t, P, b1, N, 64, 1);

    // 5. GCN layer 2: hw = h1 @ W2t ; h2 = agg(hw) + b2, lrelu
    k_mgemm<<<dim3(2, N / 128), 256, 0, stream>>>(P, W2t, Q, nullptr, N, HID, 0);
    k_aggb<<<(N + 7) / 8, 256, 0, stream>>>(Q, dinv, count, adj, b2, P, N);

    // 6. mlp0: virtual-flat split-K (S=16, Kc=448), atomic accumulate into z0acc
    k_mgemm_flat<<<dim3(2, Bn / 128, S0), 256, 0, stream>>>(P, x64, Wf0t, z0acc, Bn);

    // 7. fused tail: bias/lrelu + mlp1 + mlp2 + out
    k_tail<<<Bn / 16, 256, 0, stream>>>(z0acc, bf0, Wf1t, bf1, Wf2t, bf2, Wo, bo,
                                        d_out, flags);
}